// Round 1
// baseline (433.537 us; speedup 1.0000x reference)
//
#include <hip/hip_runtime.h>

typedef __attribute__((ext_vector_type(8))) short bf16x8;
typedef __attribute__((ext_vector_type(4))) float f32x4;
using u16 = unsigned short;

constexpr int Bsz = 4, T = 2048, C = 1024, H = 16, Dh = 64;
constexpr int Mrows = Bsz * T;   // 8192
constexpr int K_DIM = 1024;
// scores = (q.k)/sqrt(64); softmax in exp2 domain -> fold (1/8)*log2(e) into Q
constexpr float QSCALE = 0.18033688011112042f;

__device__ inline u16 f2bf(float f) {
    unsigned u = __builtin_bit_cast(unsigned, f);
    u += 0x7FFFu + ((u >> 16) & 1u);
    return (u16)(u >> 16);
}

// ---------------------------------------------------------------------------
// GEMM: C[M,N] = A[M,K] * B[N,K]^T   (B^T layout, nn.Linear weight)
// MODE 0: A = f32 x, epilogue -> split Q/K/V bf16 (B,H,T,Dh), Q pre-scaled
// MODE 1: A = bf16 attention-out, epilogue -> f32 d_out
// 128x128 tile, BK=64, 4 waves (2x2), 16x16x32 bf16 MFMA, swizzled LDS.
// ---------------------------------------------------------------------------
template<int MODE, int N_DIM>
__global__ __launch_bounds__(256)
void gemm_k(const void* __restrict__ Ap, const float* __restrict__ Bw,
            float* __restrict__ Op, u16* __restrict__ qws,
            u16* __restrict__ kws, u16* __restrict__ vws)
{
    __shared__ alignas(16) u16 As[128 * 64];
    __shared__ alignas(16) u16 Bs[128 * 64];
    const int tid = threadIdx.x;
    const int l = tid & 63, wid = tid >> 6;
    const int wm = wid >> 1, wn = wid & 1;
    const int lane16 = l & 15, lhi = l >> 4;
    const int m0 = blockIdx.x * 128, n0 = blockIdx.y * 128;

    f32x4 acc[4][4] = {};

    for (int ks = 0; ks < K_DIM / 64; ++ks) {
        __syncthreads();
        // ---- stage A tile (128 rows x 64 k) ----
        if constexpr (MODE == 0) {
            const float* A = (const float*)Ap;
            #pragma unroll
            for (int i = 0; i < 8; i++) {
                int idx = i * 256 + tid;
                int r = idx >> 4, c4 = idx & 15;
                float4 v = *(const float4*)(A + (size_t)(m0 + r) * K_DIM + ks * 64 + c4 * 4);
                unsigned lo = (unsigned)f2bf(v.x) | ((unsigned)f2bf(v.y) << 16);
                unsigned hi = (unsigned)f2bf(v.z) | ((unsigned)f2bf(v.w) << 16);
                int byte = r * 128 + c4 * 8; byte ^= (r & 7) << 4;
                *(uint2*)((char*)As + byte) = make_uint2(lo, hi);
            }
        } else {
            const u16* A = (const u16*)Ap;
            #pragma unroll
            for (int i = 0; i < 4; i++) {
                int idx = i * 256 + tid;
                int r = idx >> 3, c8 = idx & 7;
                bf16x8 v = *(const bf16x8*)(A + (size_t)(m0 + r) * K_DIM + ks * 64 + c8 * 8);
                int byte = r * 128 + c8 * 16; byte ^= (r & 7) << 4;
                *(bf16x8*)((char*)As + byte) = v;
            }
        }
        // ---- stage B tile (128 rows x 64 k), f32 weights ----
        #pragma unroll
        for (int i = 0; i < 8; i++) {
            int idx = i * 256 + tid;
            int r = idx >> 4, c4 = idx & 15;
            float4 v = *(const float4*)(Bw + (size_t)(n0 + r) * K_DIM + ks * 64 + c4 * 4);
            unsigned lo = (unsigned)f2bf(v.x) | ((unsigned)f2bf(v.y) << 16);
            unsigned hi = (unsigned)f2bf(v.z) | ((unsigned)f2bf(v.w) << 16);
            int byte = r * 128 + c4 * 8; byte ^= (r & 7) << 4;
            *(uint2*)((char*)Bs + byte) = make_uint2(lo, hi);
        }
        __syncthreads();
        // ---- compute ----
        #pragma unroll
        for (int kc = 0; kc < 2; kc++) {
            bf16x8 af[4], bfr[4];
            #pragma unroll
            for (int mi = 0; mi < 4; mi++) {
                int row = wm * 64 + mi * 16 + lane16;
                int byte = row * 128 + kc * 64 + lhi * 16; byte ^= (row & 7) << 4;
                af[mi] = *(const bf16x8*)((const char*)As + byte);
            }
            #pragma unroll
            for (int ni = 0; ni < 4; ni++) {
                int row = wn * 64 + ni * 16 + lane16;
                int byte = row * 128 + kc * 64 + lhi * 16; byte ^= (row & 7) << 4;
                bfr[ni] = *(const bf16x8*)((const char*)Bs + byte);
            }
            #pragma unroll
            for (int mi = 0; mi < 4; mi++)
                #pragma unroll
                for (int ni = 0; ni < 4; ni++)
                    acc[mi][ni] = __builtin_amdgcn_mfma_f32_16x16x32_bf16(
                        af[mi], bfr[ni], acc[mi][ni], 0, 0, 0);
        }
    }

    // ---- epilogue (C layout: col = lane&15, row = (lane>>4)*4 + r) ----
    #pragma unroll
    for (int mi = 0; mi < 4; mi++)
        #pragma unroll
        for (int ni = 0; ni < 4; ni++)
            #pragma unroll
            for (int r = 0; r < 4; r++) {
                int gm = m0 + wm * 64 + mi * 16 + lhi * 4 + r;
                int gn = n0 + wn * 64 + ni * 16 + lane16;
                float val = acc[mi][ni][r];
                if constexpr (MODE == 0) {
                    int which = gn >> 10, hh = (gn >> 6) & 15, d = gn & 63;
                    int bb = gm >> 11, t = gm & 2047;
                    size_t off = (((size_t)bb * H + hh) * T + t) * Dh + d;
                    if (which == 0)      qws[off] = f2bf(val * QSCALE);
                    else if (which == 1) kws[off] = f2bf(val);
                    else                 vws[off] = f2bf(val);
                } else {
                    Op[(size_t)gm * N_DIM + gn] = val;
                }
            }
}

// ---------------------------------------------------------------------------
// Flash attention, causal. Block = (b, h, 64-row q tile), 4 waves x 16 rows.
// KV tiles of 64 staged in LDS (K row-major swizzled, V transposed swizzled).
// Softmax in exp2 domain (Q pre-scaled). P via per-wave swizzled LDS.
// ---------------------------------------------------------------------------
__global__ __launch_bounds__(256)
void attn_k(const u16* __restrict__ qws, const u16* __restrict__ kws,
            const u16* __restrict__ vws, u16* __restrict__ ows)
{
    __shared__ alignas(16) u16 Ks[64 * 64];
    __shared__ alignas(16) u16 Vt[64 * 64];
    __shared__ alignas(16) u16 Ps[4][16 * 64];

    const int bid = blockIdx.x;
    const int qt = 31 - (bid & 31);          // long blocks first
    const int h = (bid >> 5) & 15, b = bid >> 9;
    const int tid = threadIdx.x, w = tid >> 6, l = tid & 63;
    const int lane16 = l & 15, lhi = l >> 4;

    const size_t headoff = ((size_t)b * H + h) * T * Dh;
    const u16* Q  = qws + headoff;
    const u16* Kg = kws + headoff;
    const u16* Vg = vws + headoff;
    const int qbase = qt * 64;

    const int qrow = qbase + w * 16 + lane16;
    bf16x8 qf0 = *(const bf16x8*)(Q + (size_t)qrow * Dh + lhi * 8);
    bf16x8 qf1 = *(const bf16x8*)(Q + (size_t)qrow * Dh + 32 + lhi * 8);

    f32x4 o[4] = {};
    float m[4], ls[4];
    #pragma unroll
    for (int r = 0; r < 4; r++) { m[r] = -__builtin_inff(); ls[r] = 0.f; }

    for (int kt = 0; kt <= qt; ++kt) {
        const int kv0 = kt * 64;
        __syncthreads();
        // ---- stage K (swizzled row-major) and V (transposed, swizzled) ----
        #pragma unroll
        for (int i = 0; i < 2; i++) {
            int idx = i * 256 + tid;
            int r = idx >> 3, c8 = idx & 7;
            bf16x8 kv = *(const bf16x8*)(Kg + (size_t)(kv0 + r) * Dh + c8 * 8);
            int byte = r * 128 + c8 * 16; byte ^= (r & 7) << 4;
            *(bf16x8*)((char*)Ks + byte) = kv;
            bf16x8 vv = *(const bf16x8*)(Vg + (size_t)(kv0 + r) * Dh + c8 * 8);
            #pragma unroll
            for (int j = 0; j < 8; j++) {
                int d = c8 * 8 + j;
                int vb = d * 128 + r * 2; vb ^= (d & 7) << 4;
                *(u16*)((char*)Vt + vb) = (u16)vv[j];
            }
        }
        __syncthreads();

        // ---- S = Q K^T (16 rows x 64 cols per wave) ----
        f32x4 s[4];
        #pragma unroll
        for (int ni = 0; ni < 4; ni++) {
            int krow = ni * 16 + lane16;
            int b0 = krow * 128 + lhi * 16;      b0 ^= (krow & 7) << 4;
            int b1 = krow * 128 + 64 + lhi * 16; b1 ^= (krow & 7) << 4;
            bf16x8 k0 = *(const bf16x8*)((const char*)Ks + b0);
            bf16x8 k1 = *(const bf16x8*)((const char*)Ks + b1);
            f32x4 z = {0.f, 0.f, 0.f, 0.f};
            z = __builtin_amdgcn_mfma_f32_16x16x32_bf16(qf0, k0, z, 0, 0, 0);
            z = __builtin_amdgcn_mfma_f32_16x16x32_bf16(qf1, k1, z, 0, 0, 0);
            s[ni] = z;
        }

        if (kt == qt) {   // diagonal tile: causal mask (rel indices, same base)
            #pragma unroll
            for (int ni = 0; ni < 4; ni++)
                #pragma unroll
                for (int r = 0; r < 4; r++)
                    if (ni * 16 + lane16 > w * 16 + lhi * 4 + r)
                        s[ni][r] = -__builtin_inff();
        }

        // ---- online softmax (rows live in 16 lanes sharing lhi) ----
        float pm[4];
        #pragma unroll
        for (int r = 0; r < 4; r++)
            pm[r] = fmaxf(fmaxf(s[0][r], s[1][r]), fmaxf(s[2][r], s[3][r]));
        #pragma unroll
        for (int off = 1; off < 16; off <<= 1)
            #pragma unroll
            for (int r = 0; r < 4; r++)
                pm[r] = fmaxf(pm[r], __shfl_xor(pm[r], off));

        float corr[4];
        #pragma unroll
        for (int r = 0; r < 4; r++) {
            float mn = fmaxf(m[r], pm[r]);
            corr[r] = exp2f(m[r] - mn);
            m[r] = mn;
            ls[r] *= corr[r];
        }

        u16* pw = Ps[w];
        #pragma unroll
        for (int ni = 0; ni < 4; ni++)
            #pragma unroll
            for (int r = 0; r < 4; r++) {
                float p = exp2f(s[ni][r] - m[r]);
                ls[r] += p;   // lane-partial row sum; reduced at the end
                int prow = lhi * 4 + r, pcol = ni * 16 + lane16;
                int byte = prow * 128 + pcol * 2; byte ^= (prow & 7) << 4;
                *(u16*)((char*)pw + byte) = f2bf(p);
            }

        #pragma unroll
        for (int di = 0; di < 4; di++)
            #pragma unroll
            for (int r = 0; r < 4; r++)
                o[di][r] *= corr[r];

        // ---- O += P V ----
        int pb0 = lane16 * 128 + lhi * 16;      pb0 ^= (lane16 & 7) << 4;
        int pb1 = lane16 * 128 + 64 + lhi * 16; pb1 ^= (lane16 & 7) << 4;
        bf16x8 pf0 = *(const bf16x8*)((const char*)pw + pb0);
        bf16x8 pf1 = *(const bf16x8*)((const char*)pw + pb1);
        #pragma unroll
        for (int di = 0; di < 4; di++) {
            int vrow = di * 16 + lane16;
            int vb0 = vrow * 128 + lhi * 16;      vb0 ^= (vrow & 7) << 4;
            int vb1 = vrow * 128 + 64 + lhi * 16; vb1 ^= (vrow & 7) << 4;
            bf16x8 v0 = *(const bf16x8*)((const char*)Vt + vb0);
            bf16x8 v1 = *(const bf16x8*)((const char*)Vt + vb1);
            o[di] = __builtin_amdgcn_mfma_f32_16x16x32_bf16(pf0, v0, o[di], 0, 0, 0);
            o[di] = __builtin_amdgcn_mfma_f32_16x16x32_bf16(pf1, v1, o[di], 0, 0, 0);
        }
    }

    // ---- finalize: reduce row sums across the 16 lanes, scale, store ----
    #pragma unroll
    for (int off = 1; off < 16; off <<= 1)
        #pragma unroll
        for (int r = 0; r < 4; r++)
            ls[r] += __shfl_xor(ls[r], off);

    #pragma unroll
    for (int di = 0; di < 4; di++)
        #pragma unroll
        for (int r = 0; r < 4; r++) {
            float val = o[di][r] / ls[r];
            size_t off2 = (size_t)(b * T + qbase + w * 16 + lhi * 4 + r) * C
                          + h * Dh + di * 16 + lane16;
            ows[off2] = f2bf(val);
        }
}

// ---------------------------------------------------------------------------
extern "C" void kernel_launch(void* const* d_in, const int* in_sizes, int n_in,
                              void* d_out, int out_size, void* d_ws, size_t ws_size,
                              hipStream_t stream)
{
    const float* x     = (const float*)d_in[0];
    const float* w_qkv = (const float*)d_in[1];
    const float* w_out = (const float*)d_in[2];
    float* out = (float*)d_out;

    const size_t SZ = (size_t)Bsz * H * T * Dh;  // 8388608 elems per tensor
    u16* qws = (u16*)d_ws;
    u16* kws = qws + SZ;
    u16* vws = kws + SZ;
    u16* ows = vws + SZ;   // attention output, [Mrows][C] bf16

    dim3 g0(Mrows / 128, (3 * C) / 128);
    gemm_k<0, 3 * C><<<g0, 256, 0, stream>>>(x, w_qkv, nullptr, qws, kws, vws);

    attn_k<<<dim3(Bsz * H * (T / 64)), 256, 0, stream>>>(qws, kws, vws, ows);

    dim3 g1(Mrows / 128, C / 128);
    gemm_k<1, C><<<g1, 256, 0, stream>>>(ows, w_out, out, nullptr, nullptr, nullptr);
}

// Round 2
// 382.294 us; speedup vs baseline: 1.1340x; 1.1340x over previous
//
#include <hip/hip_runtime.h>

typedef __attribute__((ext_vector_type(8))) short bf16x8;
typedef __attribute__((ext_vector_type(4))) float f32x4;
typedef __attribute__((ext_vector_type(16))) float f32x16;
typedef __attribute__((ext_vector_type(4))) int i32x4;
using u16 = unsigned short;

constexpr int Bsz = 4, T = 2048, C = 1024, H = 16, Dh = 64;
constexpr int Mrows = Bsz * T;   // 8192
constexpr int K_DIM = 1024;
// scores = (q.k)/sqrt(64); softmax in exp2 domain -> fold (1/8)*log2(e) into Q
constexpr float QSCALE = 0.18033688011112042f;

__device__ inline u16 f2bf(float f) {
    unsigned u = __builtin_bit_cast(unsigned, f);
    u += 0x7FFFu + ((u >> 16) & 1u);
    return (u16)(u >> 16);
}

__device__ inline void g2l16(const void* g, void* l) {
    __builtin_amdgcn_global_load_lds((const __attribute__((address_space(1))) void*)g,
                                     (__attribute__((address_space(3))) void*)l, 16, 0, 0);
}

// pack 2 f32 -> 2 bf16 in one u32 (lo -> low half)
__device__ inline unsigned pk2(float lo, float hi) {
    unsigned d;
    asm("v_cvt_pk_bf16_f32 %0, %1, %2" : "=v"(d) : "v"(lo), "v"(hi));
    return d;
}
// a' = (a.lo32lanes, b.lo32lanes); b' = (a.hi32lanes, b.hi32lanes)
__device__ inline void swap32(unsigned& a, unsigned& b) {
    asm("v_permlane32_swap_b32 %0, %1" : "+v"(a), "+v"(b));
}

// ---------------------------------------------------------------------------
// GEMM: C[M,N] = A[M,K] * B[N,K]^T   (B^T layout, nn.Linear weight)
// MODE 0: A = f32 x -> Q,K bf16 (B,H,T,Dh) (Q pre-scaled); V panel computed
//         with SWAPPED mfma operands so epilogue stores V^T (B,H,Dh,T).
// MODE 1: A = bf16 attention-out -> f32 d_out
// ---------------------------------------------------------------------------
template<int MODE, int N_DIM>
__global__ __launch_bounds__(256)
void gemm_k(const void* __restrict__ Ap, const float* __restrict__ Bw,
            float* __restrict__ Op, u16* __restrict__ qws,
            u16* __restrict__ kws, u16* __restrict__ vtws)
{
    __shared__ alignas(16) u16 As[128 * 64];
    __shared__ alignas(16) u16 Bs[128 * 64];
    const int tid = threadIdx.x;
    const int l = tid & 63, wid = tid >> 6;
    const int wm = wid >> 1, wn = wid & 1;
    const int lane16 = l & 15, lhi = l >> 4;
    const int m0 = blockIdx.x * 128, n0 = blockIdx.y * 128;
    const bool vpanel = (MODE == 0) && (n0 >= 2 * C);

    f32x4 acc[4][4] = {};

    for (int ks = 0; ks < K_DIM / 64; ++ks) {
        __syncthreads();
        if constexpr (MODE == 0) {
            const float* A = (const float*)Ap;
            #pragma unroll
            for (int i = 0; i < 8; i++) {
                int idx = i * 256 + tid;
                int r = idx >> 4, c4 = idx & 15;
                float4 v = *(const float4*)(A + (size_t)(m0 + r) * K_DIM + ks * 64 + c4 * 4);
                unsigned lo = (unsigned)f2bf(v.x) | ((unsigned)f2bf(v.y) << 16);
                unsigned hi = (unsigned)f2bf(v.z) | ((unsigned)f2bf(v.w) << 16);
                int byte = r * 128 + c4 * 8; byte ^= (r & 7) << 4;
                *(uint2*)((char*)As + byte) = make_uint2(lo, hi);
            }
        } else {
            const u16* A = (const u16*)Ap;
            #pragma unroll
            for (int i = 0; i < 4; i++) {
                int idx = i * 256 + tid;
                int r = idx >> 3, c8 = idx & 7;
                bf16x8 v = *(const bf16x8*)(A + (size_t)(m0 + r) * K_DIM + ks * 64 + c8 * 8);
                int byte = r * 128 + c8 * 16; byte ^= (r & 7) << 4;
                *(bf16x8*)((char*)As + byte) = v;
            }
        }
        #pragma unroll
        for (int i = 0; i < 8; i++) {
            int idx = i * 256 + tid;
            int r = idx >> 4, c4 = idx & 15;
            float4 v = *(const float4*)(Bw + (size_t)(n0 + r) * K_DIM + ks * 64 + c4 * 4);
            unsigned lo = (unsigned)f2bf(v.x) | ((unsigned)f2bf(v.y) << 16);
            unsigned hi = (unsigned)f2bf(v.z) | ((unsigned)f2bf(v.w) << 16);
            int byte = r * 128 + c4 * 8; byte ^= (r & 7) << 4;
            *(uint2*)((char*)Bs + byte) = make_uint2(lo, hi);
        }
        __syncthreads();
        #pragma unroll
        for (int kc = 0; kc < 2; kc++) {
            bf16x8 af[4], bfr[4];
            #pragma unroll
            for (int mi = 0; mi < 4; mi++) {
                int row = wm * 64 + mi * 16 + lane16;
                int byte = row * 128 + kc * 64 + lhi * 16; byte ^= (row & 7) << 4;
                af[mi] = *(const bf16x8*)((const char*)As + byte);
            }
            #pragma unroll
            for (int ni = 0; ni < 4; ni++) {
                int row = wn * 64 + ni * 16 + lane16;
                int byte = row * 128 + kc * 64 + lhi * 16; byte ^= (row & 7) << 4;
                bfr[ni] = *(const bf16x8*)((const char*)Bs + byte);
            }
            if (vpanel) {
                #pragma unroll
                for (int mi = 0; mi < 4; mi++)
                    #pragma unroll
                    for (int ni = 0; ni < 4; ni++)
                        acc[mi][ni] = __builtin_amdgcn_mfma_f32_16x16x32_bf16(
                            bfr[ni], af[mi], acc[mi][ni], 0, 0, 0);
            } else {
                #pragma unroll
                for (int mi = 0; mi < 4; mi++)
                    #pragma unroll
                    for (int ni = 0; ni < 4; ni++)
                        acc[mi][ni] = __builtin_amdgcn_mfma_f32_16x16x32_bf16(
                            af[mi], bfr[ni], acc[mi][ni], 0, 0, 0);
            }
        }
    }

    if (vpanel) {
        // D layout: regs = W rows (out-features), lanes = x rows (t)
        #pragma unroll
        for (int mi = 0; mi < 4; mi++)
            #pragma unroll
            for (int ni = 0; ni < 4; ni++)
                #pragma unroll
                for (int r = 0; r < 4; r++) {
                    int wr = n0 + wn * 64 + ni * 16 + lhi * 4 + r;  // 2048..3071
                    int tg = m0 + wm * 64 + mi * 16 + lane16;       // 0..8191
                    int hh = (wr >> 6) & 15, d = wr & 63;
                    int bb = tg >> 11, tt = tg & 2047;
                    size_t off = (((size_t)bb * H + hh) * Dh + d) * T + tt;
                    vtws[off] = f2bf(acc[mi][ni][r]);
                }
    } else {
        #pragma unroll
        for (int mi = 0; mi < 4; mi++)
            #pragma unroll
            for (int ni = 0; ni < 4; ni++)
                #pragma unroll
                for (int r = 0; r < 4; r++) {
                    int gm = m0 + wm * 64 + mi * 16 + lhi * 4 + r;
                    int gn = n0 + wn * 64 + ni * 16 + lane16;
                    float val = acc[mi][ni][r];
                    if constexpr (MODE == 0) {
                        int hh = (gn >> 6) & 15, d = gn & 63;
                        int bb = gm >> 11, t = gm & 2047;
                        size_t off = (((size_t)bb * H + hh) * T + t) * Dh + d;
                        if (gn < C) qws[off] = f2bf(val * QSCALE);
                        else        kws[off] = f2bf(val);
                    } else {
                        Op[(size_t)gm * N_DIM + gn] = val;
                    }
                }
    }
}

// ---------------------------------------------------------------------------
// Flash attention, causal — swapped-QK 32x32 structure (m214 port).
// Block = 4 waves x 64 q-rows = 256 q-rows. KV tiles of 64, double-buffered
// LDS: K [64t][64d] and V^T [64d][64t], both XOR-swizzled via pre-swizzled
// global_load_lds source. Softmax fully in-register (P-row lane-local),
// P->bf16 A-frags via v_cvt_pk_bf16_f32 + v_permlane32_swap_b32.
// ---------------------------------------------------------------------------
__device__ inline bf16x8 ldsfrag(const u16* base, int row, int cc) {
    int byte = (row << 7) + (cc << 4); byte ^= (row & 7) << 4;
    return *(const bf16x8*)((const char*)base + byte);
}

// stage 64 rows x 128B, source chunk-swizzled so swizzled reads see row-major
__device__ inline void stage_t(u16* lds, const u16* gb, int rstride, int tid) {
    #pragma unroll
    for (int it = 0; it < 2; ++it) {
        int chunk = it * 256 + tid;
        int r = chunk >> 3, cc = chunk & 7;
        int sc = cc ^ (r & 7);
        g2l16(gb + (size_t)r * rstride + sc * 8, lds + (it * 256 + (tid & 192)) * 8);
    }
}

__global__ __launch_bounds__(256, 2)
void attn_k(const u16* __restrict__ qws, const u16* __restrict__ kws,
            const u16* __restrict__ vtws, u16* __restrict__ ows)
{
    __shared__ alignas(16) u16 KL[2][64 * 64];
    __shared__ alignas(16) u16 VL[2][64 * 64];

    const int bid = blockIdx.x;
    // complementary (long,short) pairing across the two residency rounds
    const int qt   = (bid < 256) ? 7 - (bid & 7) : (bid & 7);
    const int head = ((bid < 256) ? 0 : 32) + ((bid & 255) >> 3);
    const int b = head >> 4, h = head & 15;
    const int tid = threadIdx.x, w = tid >> 6, l = tid & 63;
    const int l31 = l & 31, hi = l >> 5;

    const size_t hoff = (size_t)head * (T * Dh);
    const u16* Qg  = qws + hoff;
    const u16* Kg  = kws + hoff;
    const u16* Vtg = vtws + hoff;   // [Dh][T] per head

    const int qb_w = qt * 256 + w * 64;
    const int nt = 4 * qt + 4;

    // Q fragments in registers (B-operand: row q = l&31, k = hi*8+j)
    bf16x8 qf[2][4];
    #pragma unroll
    for (int q2 = 0; q2 < 2; ++q2)
        #pragma unroll
        for (int c = 0; c < 4; ++c)
            qf[q2][c] = *(const bf16x8*)(Qg + (size_t)(qb_w + q2 * 32 + l31) * Dh
                                         + c * 16 + hi * 8);

    f32x16 o[2][2] = {};                       // [qblk][dblk]
    float mrun[2] = {-__builtin_inff(), -__builtin_inff()};
    float lrun[2] = {0.f, 0.f};

    stage_t(KL[0], Kg, Dh, tid);
    stage_t(VL[0], Vtg, T, tid);
    __syncthreads();

    for (int t = 0; t < nt; ++t) {
        const int cur = t & 1;
        if (t + 1 < nt) {
            stage_t(KL[cur ^ 1], Kg + (size_t)(t + 1) * 64 * Dh, Dh, tid);
            stage_t(VL[cur ^ 1], Vtg + (t + 1) * 64, T, tid);
        }
        const int kv0 = t * 64;
        if (kv0 <= qb_w + 63) {
            const u16* Kb = KL[cur];
            const u16* Vb = VL[cur];

            bf16x8 kf[2][4];   // A-operand: row kv = l&31 (+32*kvh), k = hi*8+j
            #pragma unroll
            for (int kvh = 0; kvh < 2; ++kvh)
                #pragma unroll
                for (int c = 0; c < 4; ++c)
                    kf[kvh][c] = ldsfrag(Kb, kvh * 32 + l31, c * 2 + hi);

            unsigned paf[2][4][4];
            const bool act0 = kv0 <= qb_w + 31;

            #pragma unroll
            for (int q2 = 0; q2 < 2; ++q2) {
                if (q2 == 0 && !act0) continue;
                f32x16 s0{}, s1{};
                #pragma unroll
                for (int c = 0; c < 4; ++c) {
                    s0 = __builtin_amdgcn_mfma_f32_32x32x16_bf16(kf[0][c], qf[q2][c], s0, 0, 0, 0);
                    s1 = __builtin_amdgcn_mfma_f32_32x32x16_bf16(kf[1][c], qf[q2][c], s1, 0, 0, 0);
                }
                const int qbb = qb_w + q2 * 32;
                if (kv0 + 63 > qbb) {          // diagonal: causal mask
                    int qg = qbb + l31;
                    #pragma unroll
                    for (int r = 0; r < 16; ++r) {
                        int kvg = kv0 + (r & 3) + 8 * (r >> 2) + 4 * hi;
                        if (kvg > qg)      s0[r] = -__builtin_inff();
                        if (kvg + 32 > qg) s1[r] = -__builtin_inff();
                    }
                }
                // ---- in-register online softmax (row q = l&31, pair lane l^32) ----
                float pmax = s0[0];
                #pragma unroll
                for (int r = 1; r < 16; ++r) pmax = fmaxf(pmax, s0[r]);
                #pragma unroll
                for (int r = 0; r < 16; ++r) pmax = fmaxf(pmax, s1[r]);
                pmax = fmaxf(pmax, __shfl_xor(pmax, 32));

                if (!__all(pmax - mrun[q2] <= 8.0f)) {   // T13 defer-max
                    float mn = fmaxf(mrun[q2], pmax);
                    float corr = __builtin_amdgcn_exp2f(mrun[q2] - mn);
                    mrun[q2] = mn;
                    lrun[q2] *= corr;
                    #pragma unroll
                    for (int r = 0; r < 16; ++r) {
                        float cr = __shfl(corr, (r & 3) + 8 * (r >> 2) + 4 * hi);
                        o[q2][0][r] *= cr;
                        o[q2][1][r] *= cr;
                    }
                }
                float p0[16], p1[16];
                #pragma unroll
                for (int r = 0; r < 16; ++r) {
                    p0[r] = __builtin_amdgcn_exp2f(s0[r] - mrun[q2]);
                    p1[r] = __builtin_amdgcn_exp2f(s1[r] - mrun[q2]);
                    lrun[q2] += p0[r] + p1[r];
                }
                // ---- P -> bf16 A-frags (T12: cvt_pk + permlane32_swap) ----
                unsigned cc[8];
                #pragma unroll
                for (int i = 0; i < 4; ++i) cc[i]     = pk2(p0[2 * i], p0[2 * i + 1]);
                #pragma unroll
                for (int i = 0; i < 4; ++i) cc[4 + i] = pk2(p0[8 + 2 * i], p0[9 + 2 * i]);
                swap32(cc[0], cc[2]); swap32(cc[1], cc[3]);
                swap32(cc[4], cc[6]); swap32(cc[5], cc[7]);
                #pragma unroll
                for (int i = 0; i < 4; ++i) { paf[q2][0][i] = cc[i]; paf[q2][1][i] = cc[4 + i]; }
                #pragma unroll
                for (int i = 0; i < 4; ++i) cc[i]     = pk2(p1[2 * i], p1[2 * i + 1]);
                #pragma unroll
                for (int i = 0; i < 4; ++i) cc[4 + i] = pk2(p1[8 + 2 * i], p1[9 + 2 * i]);
                swap32(cc[0], cc[2]); swap32(cc[1], cc[3]);
                swap32(cc[4], cc[6]); swap32(cc[5], cc[7]);
                #pragma unroll
                for (int i = 0; i < 4; ++i) { paf[q2][2][i] = cc[i]; paf[q2][3][i] = cc[4 + i]; }
            }

            bf16x8 vf[2][4];   // B-operand: row d = l&31 (+32*dblk), k = kv = hi*8+j
            #pragma unroll
            for (int db = 0; db < 2; ++db)
                #pragma unroll
                for (int kb = 0; kb < 4; ++kb)
                    vf[db][kb] = ldsfrag(Vb, db * 32 + l31, kb * 2 + hi);

            #pragma unroll
            for (int q2 = 0; q2 < 2; ++q2) {
                if (q2 == 0 && !act0) continue;
                #pragma unroll
                for (int db = 0; db < 2; ++db)
                    #pragma unroll
                    for (int kb = 0; kb < 4; ++kb) {
                        i32x4 wv = {(int)paf[q2][kb][0], (int)paf[q2][kb][1],
                                    (int)paf[q2][kb][2], (int)paf[q2][kb][3]};
                        o[q2][db] = __builtin_amdgcn_mfma_f32_32x32x16_bf16(
                            __builtin_bit_cast(bf16x8, wv), vf[db][kb], o[q2][db], 0, 0, 0);
                    }
            }
        }
        __syncthreads();
    }

    // ---- finalize ----
    #pragma unroll
    for (int q2 = 0; q2 < 2; ++q2) {
        float lt = lrun[q2] + __shfl_xor(lrun[q2], 32);
        float inv = 1.0f / lt;
        int qbb = qb_w + q2 * 32;
        #pragma unroll
        for (int r = 0; r < 16; ++r) {
            int cr = (r & 3) + 8 * (r >> 2) + 4 * hi;
            float il = __shfl(inv, cr);
            size_t rowoff = ((size_t)b * T + qbb + cr) * C + h * Dh + l31;
            ows[rowoff]      = f2bf(o[q2][0][r] * il);
            ows[rowoff + 32] = f2bf(o[q2][1][r] * il);
        }
    }
}

// ---------------------------------------------------------------------------
extern "C" void kernel_launch(void* const* d_in, const int* in_sizes, int n_in,
                              void* d_out, int out_size, void* d_ws, size_t ws_size,
                              hipStream_t stream)
{
    const float* x     = (const float*)d_in[0];
    const float* w_qkv = (const float*)d_in[1];
    const float* w_out = (const float*)d_in[2];
    float* out = (float*)d_out;

    const size_t SZ = (size_t)Bsz * H * T * Dh;  // 8388608 elems per tensor
    u16* qws  = (u16*)d_ws;
    u16* kws  = qws + SZ;
    u16* vtws = kws + SZ;   // V transposed: [B][H][Dh][T]
    u16* ows  = vtws + SZ;  // attention output, [Mrows][C] bf16

    dim3 g0(Mrows / 128, (3 * C) / 128);
    gemm_k<0, 3 * C><<<g0, 256, 0, stream>>>(x, w_qkv, nullptr, qws, kws, vtws);

    attn_k<<<dim3(512), 256, 0, stream>>>(qws, kws, vtws, ows);

    dim3 g1(Mrows / 128, C / 128);
    gemm_k<1, C><<<g1, 256, 0, stream>>>(ows, w_out, out, nullptr, nullptr, nullptr);
}

// Round 3
// 272.235 us; speedup vs baseline: 1.5925x; 1.4043x over previous
//
#include <hip/hip_runtime.h>

typedef __attribute__((ext_vector_type(8))) short bf16x8;
typedef __attribute__((ext_vector_type(4))) float f32x4;
typedef __attribute__((ext_vector_type(16))) float f32x16;
typedef __attribute__((ext_vector_type(4))) int i32x4;
using u16 = unsigned short;

constexpr int Bsz = 4, T = 2048, C = 1024, H = 16, Dh = 64;
constexpr int Mrows = Bsz * T;   // 8192
constexpr int K_DIM = 1024;
// scores = (q.k)/sqrt(64); softmax in exp2 domain -> fold (1/8)*log2(e) into Q
constexpr float QSCALE = 0.18033688011112042f;

__device__ inline u16 f2bf(float f) {
    unsigned u = __builtin_bit_cast(unsigned, f);
    u += 0x7FFFu + ((u >> 16) & 1u);
    return (u16)(u >> 16);
}

__device__ inline void g2l16(const void* g, void* l) {
    __builtin_amdgcn_global_load_lds((const __attribute__((address_space(1))) void*)g,
                                     (__attribute__((address_space(3))) void*)l, 16, 0, 0);
}

// pack 2 f32 -> 2 bf16 in one u32 (lo -> low half)
__device__ inline unsigned pk2(float lo, float hi) {
    unsigned d;
    asm("v_cvt_pk_bf16_f32 %0, %1, %2" : "=v"(d) : "v"(lo), "v"(hi));
    return d;
}
// a' = (a.lo32lanes, b.lo32lanes); b' = (a.hi32lanes, b.hi32lanes)
__device__ inline void swap32(unsigned& a, unsigned& b) {
    asm("v_permlane32_swap_b32 %0, %1" : "+v"(a), "+v"(b));
}

// ---------------------------------------------------------------------------
// GEMM: C[M,N] = A[M,K] * B[N,K]^T   (B^T layout, nn.Linear weight)
// MODE 0: A = f32 x, columns [0,2C)   -> Q,K bf16 (B,H,T,Dh), Q pre-scaled
// MODE 2: A = f32 x, columns [2C,3C)  -> SWAPPED mfma operands, stores V^T
//         (B,H,Dh,T). Compile-time split so each body is branch-free (the
//         round-2 runtime `vpanel` branch cost 3x: MfmaUtil 6%, stall-bound).
// MODE 1: A = bf16 attention-out -> f32 d_out
// 128x128 tile, BK=64, 4 waves (2x2), 16x16x32 bf16 MFMA, swizzled LDS.
// ---------------------------------------------------------------------------
template<int MODE>
__global__ __launch_bounds__(256)
void gemm_k(const void* __restrict__ Ap, const float* __restrict__ Bw,
            float* __restrict__ Op, u16* __restrict__ qws,
            u16* __restrict__ kws, u16* __restrict__ vtws)
{
    __shared__ alignas(16) u16 As[128 * 64];
    __shared__ alignas(16) u16 Bs[128 * 64];
    const int tid = threadIdx.x;
    const int l = tid & 63, wid = tid >> 6;
    const int wm = wid >> 1, wn = wid & 1;
    const int lane16 = l & 15, lhi = l >> 4;
    const int m0 = blockIdx.x * 128;
    const int n0 = (MODE == 2 ? 2 * C : 0) + blockIdx.y * 128;

    f32x4 acc[4][4] = {};

    for (int ks = 0; ks < K_DIM / 64; ++ks) {
        __syncthreads();
        // ---- stage A tile (128 rows x 64 k) ----
        if constexpr (MODE != 1) {
            const float* A = (const float*)Ap;
            #pragma unroll
            for (int i = 0; i < 8; i++) {
                int idx = i * 256 + tid;
                int r = idx >> 4, c4 = idx & 15;
                float4 v = *(const float4*)(A + (size_t)(m0 + r) * K_DIM + ks * 64 + c4 * 4);
                unsigned lo = (unsigned)f2bf(v.x) | ((unsigned)f2bf(v.y) << 16);
                unsigned hi = (unsigned)f2bf(v.z) | ((unsigned)f2bf(v.w) << 16);
                int byte = r * 128 + c4 * 8; byte ^= (r & 7) << 4;
                *(uint2*)((char*)As + byte) = make_uint2(lo, hi);
            }
        } else {
            const u16* A = (const u16*)Ap;
            #pragma unroll
            for (int i = 0; i < 4; i++) {
                int idx = i * 256 + tid;
                int r = idx >> 3, c8 = idx & 7;
                bf16x8 v = *(const bf16x8*)(A + (size_t)(m0 + r) * K_DIM + ks * 64 + c8 * 8);
                int byte = r * 128 + c8 * 16; byte ^= (r & 7) << 4;
                *(bf16x8*)((char*)As + byte) = v;
            }
        }
        // ---- stage B tile (128 rows x 64 k), f32 weights ----
        #pragma unroll
        for (int i = 0; i < 8; i++) {
            int idx = i * 256 + tid;
            int r = idx >> 4, c4 = idx & 15;
            float4 v = *(const float4*)(Bw + (size_t)(n0 + r) * K_DIM + ks * 64 + c4 * 4);
            unsigned lo = (unsigned)f2bf(v.x) | ((unsigned)f2bf(v.y) << 16);
            unsigned hi = (unsigned)f2bf(v.z) | ((unsigned)f2bf(v.w) << 16);
            int byte = r * 128 + c4 * 8; byte ^= (r & 7) << 4;
            *(uint2*)((char*)Bs + byte) = make_uint2(lo, hi);
        }
        __syncthreads();
        // ---- compute (branch-free per instantiation) ----
        #pragma unroll
        for (int kc = 0; kc < 2; kc++) {
            bf16x8 af[4], bfr[4];
            #pragma unroll
            for (int mi = 0; mi < 4; mi++) {
                int row = wm * 64 + mi * 16 + lane16;
                int byte = row * 128 + kc * 64 + lhi * 16; byte ^= (row & 7) << 4;
                af[mi] = *(const bf16x8*)((const char*)As + byte);
            }
            #pragma unroll
            for (int ni = 0; ni < 4; ni++) {
                int row = wn * 64 + ni * 16 + lane16;
                int byte = row * 128 + kc * 64 + lhi * 16; byte ^= (row & 7) << 4;
                bfr[ni] = *(const bf16x8*)((const char*)Bs + byte);
            }
            #pragma unroll
            for (int mi = 0; mi < 4; mi++)
                #pragma unroll
                for (int ni = 0; ni < 4; ni++) {
                    if constexpr (MODE == 2)
                        acc[mi][ni] = __builtin_amdgcn_mfma_f32_16x16x32_bf16(
                            bfr[ni], af[mi], acc[mi][ni], 0, 0, 0);
                    else
                        acc[mi][ni] = __builtin_amdgcn_mfma_f32_16x16x32_bf16(
                            af[mi], bfr[ni], acc[mi][ni], 0, 0, 0);
                }
        }
    }

    if constexpr (MODE == 2) {
        // D layout: regs = W rows (out-features), lanes = x rows (t)
        #pragma unroll
        for (int mi = 0; mi < 4; mi++)
            #pragma unroll
            for (int ni = 0; ni < 4; ni++)
                #pragma unroll
                for (int r = 0; r < 4; r++) {
                    int wr = n0 + wn * 64 + ni * 16 + lhi * 4 + r;  // 2048..3071
                    int tg = m0 + wm * 64 + mi * 16 + lane16;       // 0..8191
                    int hh = (wr >> 6) & 15, d = wr & 63;
                    int bb = tg >> 11, tt = tg & 2047;
                    size_t off = (((size_t)bb * H + hh) * Dh + d) * T + tt;
                    vtws[off] = f2bf(acc[mi][ni][r]);
                }
    } else {
        #pragma unroll
        for (int mi = 0; mi < 4; mi++)
            #pragma unroll
            for (int ni = 0; ni < 4; ni++)
                #pragma unroll
                for (int r = 0; r < 4; r++) {
                    int gm = m0 + wm * 64 + mi * 16 + lhi * 4 + r;
                    int gn = n0 + wn * 64 + ni * 16 + lane16;
                    float val = acc[mi][ni][r];
                    if constexpr (MODE == 0) {
                        int hh = (gn >> 6) & 15, d = gn & 63;
                        int bb = gm >> 11, t = gm & 2047;
                        size_t off = (((size_t)bb * H + hh) * T + t) * Dh + d;
                        if (gn < C) qws[off] = f2bf(val * QSCALE);
                        else        kws[off] = f2bf(val);
                    } else {
                        Op[(size_t)gm * C + gn] = val;
                    }
                }
    }
}

// ---------------------------------------------------------------------------
// Flash attention, causal — swapped-QK 32x32 structure (m214 port).
// Block = 4 waves x 64 q-rows = 256 q-rows. KV tiles of 64, double-buffered
// LDS: K [64t][64d] and V^T [64d][64t], both XOR-swizzled via pre-swizzled
// global_load_lds source. Softmax fully in-register (P-row lane-local),
// P->bf16 A-frags via v_cvt_pk_bf16_f32 + v_permlane32_swap_b32.
// ---------------------------------------------------------------------------
__device__ inline bf16x8 ldsfrag(const u16* base, int row, int cc) {
    int byte = (row << 7) + (cc << 4); byte ^= (row & 7) << 4;
    return *(const bf16x8*)((const char*)base + byte);
}

// stage 64 rows x 128B, source chunk-swizzled so swizzled reads see row-major
__device__ inline void stage_t(u16* lds, const u16* gb, int rstride, int tid) {
    #pragma unroll
    for (int it = 0; it < 2; ++it) {
        int chunk = it * 256 + tid;
        int r = chunk >> 3, cc = chunk & 7;
        int sc = cc ^ (r & 7);
        g2l16(gb + (size_t)r * rstride + sc * 8, lds + (it * 256 + (tid & 192)) * 8);
    }
}

__global__ __launch_bounds__(256, 2)
void attn_k(const u16* __restrict__ qws, const u16* __restrict__ kws,
            const u16* __restrict__ vtws, u16* __restrict__ ows)
{
    __shared__ alignas(16) u16 KL[2][64 * 64];
    __shared__ alignas(16) u16 VL[2][64 * 64];

    const int bid = blockIdx.x;
    // complementary (long,short) pairing across the two residency rounds
    const int qt   = (bid < 256) ? 7 - (bid & 7) : (bid & 7);
    const int head = ((bid < 256) ? 0 : 32) + ((bid & 255) >> 3);
    const int b = head >> 4, h = head & 15;
    const int tid = threadIdx.x, w = tid >> 6, l = tid & 63;
    const int l31 = l & 31, hi = l >> 5;

    const size_t hoff = (size_t)head * (T * Dh);
    const u16* Qg  = qws + hoff;
    const u16* Kg  = kws + hoff;
    const u16* Vtg = vtws + hoff;   // [Dh][T] per head

    const int qb_w = qt * 256 + w * 64;
    const int nt = 4 * qt + 4;

    // Q fragments in registers (B-operand: row q = l&31, k = hi*8+j)
    bf16x8 qf[2][4];
    #pragma unroll
    for (int q2 = 0; q2 < 2; ++q2)
        #pragma unroll
        for (int c = 0; c < 4; ++c)
            qf[q2][c] = *(const bf16x8*)(Qg + (size_t)(qb_w + q2 * 32 + l31) * Dh
                                         + c * 16 + hi * 8);

    f32x16 o[2][2] = {};                       // [qblk][dblk]
    float mrun[2] = {-__builtin_inff(), -__builtin_inff()};
    float lrun[2] = {0.f, 0.f};

    stage_t(KL[0], Kg, Dh, tid);
    stage_t(VL[0], Vtg, T, tid);
    __syncthreads();

    for (int t = 0; t < nt; ++t) {
        const int cur = t & 1;
        if (t + 1 < nt) {
            stage_t(KL[cur ^ 1], Kg + (size_t)(t + 1) * 64 * Dh, Dh, tid);
            stage_t(VL[cur ^ 1], Vtg + (t + 1) * 64, T, tid);
        }
        const int kv0 = t * 64;
        if (kv0 <= qb_w + 63) {
            const u16* Kb = KL[cur];
            const u16* Vb = VL[cur];

            bf16x8 kf[2][4];   // A-operand: row kv = l&31 (+32*kvh), k = hi*8+j
            #pragma unroll
            for (int kvh = 0; kvh < 2; ++kvh)
                #pragma unroll
                for (int c = 0; c < 4; ++c)
                    kf[kvh][c] = ldsfrag(Kb, kvh * 32 + l31, c * 2 + hi);

            unsigned paf[2][4][4];
            const bool act0 = kv0 <= qb_w + 31;

            #pragma unroll
            for (int q2 = 0; q2 < 2; ++q2) {
                if (q2 == 0 && !act0) continue;
                f32x16 s0{}, s1{};
                #pragma unroll
                for (int c = 0; c < 4; ++c) {
                    s0 = __builtin_amdgcn_mfma_f32_32x32x16_bf16(kf[0][c], qf[q2][c], s0, 0, 0, 0);
                    s1 = __builtin_amdgcn_mfma_f32_32x32x16_bf16(kf[1][c], qf[q2][c], s1, 0, 0, 0);
                }
                const int qbb = qb_w + q2 * 32;
                if (kv0 + 63 > qbb) {          // diagonal: causal mask
                    int qg = qbb + l31;
                    #pragma unroll
                    for (int r = 0; r < 16; ++r) {
                        int kvg = kv0 + (r & 3) + 8 * (r >> 2) + 4 * hi;
                        if (kvg > qg)      s0[r] = -__builtin_inff();
                        if (kvg + 32 > qg) s1[r] = -__builtin_inff();
                    }
                }
                // ---- in-register online softmax (row q = l&31, pair lane l^32) ----
                float pmax = s0[0];
                #pragma unroll
                for (int r = 1; r < 16; ++r) pmax = fmaxf(pmax, s0[r]);
                #pragma unroll
                for (int r = 0; r < 16; ++r) pmax = fmaxf(pmax, s1[r]);
                pmax = fmaxf(pmax, __shfl_xor(pmax, 32));

                if (!__all(pmax - mrun[q2] <= 8.0f)) {   // T13 defer-max
                    float mn = fmaxf(mrun[q2], pmax);
                    float corr = __builtin_amdgcn_exp2f(mrun[q2] - mn);
                    mrun[q2] = mn;
                    lrun[q2] *= corr;
                    #pragma unroll
                    for (int r = 0; r < 16; ++r) {
                        float cr = __shfl(corr, (r & 3) + 8 * (r >> 2) + 4 * hi);
                        o[q2][0][r] *= cr;
                        o[q2][1][r] *= cr;
                    }
                }
                float p0[16], p1[16];
                #pragma unroll
                for (int r = 0; r < 16; ++r) {
                    p0[r] = __builtin_amdgcn_exp2f(s0[r] - mrun[q2]);
                    p1[r] = __builtin_amdgcn_exp2f(s1[r] - mrun[q2]);
                    lrun[q2] += p0[r] + p1[r];
                }
                // ---- P -> bf16 A-frags (T12: cvt_pk + permlane32_swap) ----
                unsigned cc[8];
                #pragma unroll
                for (int i = 0; i < 4; ++i) cc[i]     = pk2(p0[2 * i], p0[2 * i + 1]);
                #pragma unroll
                for (int i = 0; i < 4; ++i) cc[4 + i] = pk2(p0[8 + 2 * i], p0[9 + 2 * i]);
                swap32(cc[0], cc[2]); swap32(cc[1], cc[3]);
                swap32(cc[4], cc[6]); swap32(cc[5], cc[7]);
                #pragma unroll
                for (int i = 0; i < 4; ++i) { paf[q2][0][i] = cc[i]; paf[q2][1][i] = cc[4 + i]; }
                #pragma unroll
                for (int i = 0; i < 4; ++i) cc[i]     = pk2(p1[2 * i], p1[2 * i + 1]);
                #pragma unroll
                for (int i = 0; i < 4; ++i) cc[4 + i] = pk2(p1[8 + 2 * i], p1[9 + 2 * i]);
                swap32(cc[0], cc[2]); swap32(cc[1], cc[3]);
                swap32(cc[4], cc[6]); swap32(cc[5], cc[7]);
                #pragma unroll
                for (int i = 0; i < 4; ++i) { paf[q2][2][i] = cc[i]; paf[q2][3][i] = cc[4 + i]; }
            }

            bf16x8 vf[2][4];   // B-operand: row d = l&31 (+32*dblk), k = kv = hi*8+j
            #pragma unroll
            for (int db = 0; db < 2; ++db)
                #pragma unroll
                for (int kb = 0; kb < 4; ++kb)
                    vf[db][kb] = ldsfrag(Vb, db * 32 + l31, kb * 2 + hi);

            #pragma unroll
            for (int q2 = 0; q2 < 2; ++q2) {
                if (q2 == 0 && !act0) continue;
                #pragma unroll
                for (int db = 0; db < 2; ++db)
                    #pragma unroll
                    for (int kb = 0; kb < 4; ++kb) {
                        i32x4 wv = {(int)paf[q2][kb][0], (int)paf[q2][kb][1],
                                    (int)paf[q2][kb][2], (int)paf[q2][kb][3]};
                        o[q2][db] = __builtin_amdgcn_mfma_f32_32x32x16_bf16(
                            __builtin_bit_cast(bf16x8, wv), vf[db][kb], o[q2][db], 0, 0, 0);
                    }
            }
        }
        __syncthreads();
    }

    // ---- finalize ----
    #pragma unroll
    for (int q2 = 0; q2 < 2; ++q2) {
        float lt = lrun[q2] + __shfl_xor(lrun[q2], 32);
        float inv = 1.0f / lt;
        int qbb = qb_w + q2 * 32;
        #pragma unroll
        for (int r = 0; r < 16; ++r) {
            int cr = (r & 3) + 8 * (r >> 2) + 4 * hi;
            float il = __shfl(inv, cr);
            size_t rowoff = ((size_t)b * T + qbb + cr) * C + h * Dh + l31;
            ows[rowoff]      = f2bf(o[q2][0][r] * il);
            ows[rowoff + 32] = f2bf(o[q2][1][r] * il);
        }
    }
}

// ---------------------------------------------------------------------------
extern "C" void kernel_launch(void* const* d_in, const int* in_sizes, int n_in,
                              void* d_out, int out_size, void* d_ws, size_t ws_size,
                              hipStream_t stream)
{
    const float* x     = (const float*)d_in[0];
    const float* w_qkv = (const float*)d_in[1];
    const float* w_out = (const float*)d_in[2];
    float* out = (float*)d_out;

    const size_t SZ = (size_t)Bsz * H * T * Dh;  // 8388608 elems per tensor
    u16* qws  = (u16*)d_ws;
    u16* kws  = qws + SZ;
    u16* vtws = kws + SZ;   // V transposed: [B][H][Dh][T]
    u16* ows  = vtws + SZ;  // attention output, [Mrows][C] bf16

    dim3 gqk(Mrows / 128, (2 * C) / 128);
    gemm_k<0><<<gqk, 256, 0, stream>>>(x, w_qkv, nullptr, qws, kws, vtws);
    dim3 gv(Mrows / 128, C / 128);
    gemm_k<2><<<gv, 256, 0, stream>>>(x, w_qkv, nullptr, qws, kws, vtws);

    attn_k<<<dim3(512), 256, 0, stream>>>(qws, kws, vtws, ows);

    dim3 g1(Mrows / 128, C / 128);
    gemm_k<1><<<g1, 256, 0, stream>>>(ows, w_out, out, nullptr, nullptr, nullptr);
}

// Round 4
// 175.443 us; speedup vs baseline: 2.4711x; 1.5517x over previous
//
#include <hip/hip_runtime.h>

typedef __attribute__((ext_vector_type(8))) short bf16x8;
typedef __attribute__((ext_vector_type(4))) float f32x4;
typedef __attribute__((ext_vector_type(16))) float f32x16;
typedef __attribute__((ext_vector_type(4))) int i32x4;
using u16 = unsigned short;

constexpr int Bsz = 4, T = 2048, C = 1024, H = 16, Dh = 64;
constexpr int Mrows = Bsz * T;   // 8192
constexpr int K_DIM = 1024;
// scores = (q.k)/sqrt(64); softmax in exp2 domain -> fold (1/8)*log2(e) into Q
constexpr float QSCALE = 0.18033688011112042f;

__device__ inline u16 f2bf(float f) {
    unsigned u = __builtin_bit_cast(unsigned, f);
    u += 0x7FFFu + ((u >> 16) & 1u);
    return (u16)(u >> 16);
}

__device__ inline void g2l16(const void* g, void* l) {
    __builtin_amdgcn_global_load_lds((const __attribute__((address_space(1))) void*)g,
                                     (__attribute__((address_space(3))) void*)l, 16, 0, 0);
}

// pack 2 f32 -> 2 bf16 in one u32 (lo -> low half)
__device__ inline unsigned pk2(float lo, float hi) {
    unsigned d;
    asm("v_cvt_pk_bf16_f32 %0, %1, %2" : "=v"(d) : "v"(lo), "v"(hi));
    return d;
}
// a' = (a.lo32lanes, b.lo32lanes); b' = (a.hi32lanes, b.hi32lanes)
__device__ inline void swap32(unsigned& a, unsigned& b) {
    asm("v_permlane32_swap_b32 %0, %1" : "+v"(a), "+v"(b));
}

// ---------------------------------------------------------------------------
// One-shot f32 -> bf16 conversion of x, w_qkv, w_out (memory-bound, ~15us).
// Chunk = 8 elems. Ranges: x 1048576 chunks, w_qkv 393216, w_out 131072.
// ---------------------------------------------------------------------------
__global__ __launch_bounds__(256)
void cvt_k(const float* __restrict__ x, const float* __restrict__ wq,
           const float* __restrict__ wo, u16* __restrict__ xb,
           u16* __restrict__ wqb, u16* __restrict__ wob)
{
    int idx = blockIdx.x * 256 + threadIdx.x;
    const float* src; u16* dst; int rel;
    if (idx < 1048576)      { src = x;  dst = xb;  rel = idx; }
    else if (idx < 1441792) { src = wq; dst = wqb; rel = idx - 1048576; }
    else                    { src = wo; dst = wob; rel = idx - 1441792; }
    size_t off = (size_t)rel * 8;
    float4 a = *(const float4*)(src + off);
    float4 b = *(const float4*)(src + off + 4);
    unsigned r0 = (unsigned)f2bf(a.x) | ((unsigned)f2bf(a.y) << 16);
    unsigned r1 = (unsigned)f2bf(a.z) | ((unsigned)f2bf(a.w) << 16);
    unsigned r2 = (unsigned)f2bf(b.x) | ((unsigned)f2bf(b.y) << 16);
    unsigned r3 = (unsigned)f2bf(b.z) | ((unsigned)f2bf(b.w) << 16);
    *(uint4*)(dst + off) = make_uint4(r0, r1, r2, r3);
}

// ---------------------------------------------------------------------------
// m97-structure GEMM: C[M,N] = A[M,K] * B[N,K]^T, all-bf16 inputs.
// 128x128 tile, BK=64, 4 waves (2x2), global_load_lds dwordx4 staging with
// pre-swizzled global source (T2 both-sides), 2-barrier K-loop.
// MODE 0: -> Q,K bf16 (B,H,T,Dh), Q pre-scaled.   MODE 2: swapped mfma
// operands -> V^T (B,H,Dh,T).   MODE 1: bf16 attn-out -> f32 d_out.
// ---------------------------------------------------------------------------
__device__ inline void stage_g(u16* lds, const u16* gb, int ldg, int tid) {
    #pragma unroll
    for (int i = 0; i < 4; ++i) {
        int ch = i * 256 + tid;
        int r = ch >> 3, c8 = ch & 7;
        int sc = c8 ^ (r & 7);   // inverse-swizzled source, linear LDS dest
        g2l16(gb + (size_t)r * ldg + sc * 8, lds + (i * 256 + (tid & 192)) * 8);
    }
}

template<int MODE>
__global__ __launch_bounds__(256)
void gemm_k(const u16* __restrict__ Ab, const u16* __restrict__ Bb,
            float* __restrict__ Op, u16* __restrict__ qws,
            u16* __restrict__ kws, u16* __restrict__ vtws)
{
    __shared__ alignas(16) u16 As[128 * 64];
    __shared__ alignas(16) u16 Bs[128 * 64];
    const int tid = threadIdx.x;
    const int l = tid & 63, wid = tid >> 6;
    const int wm = wid >> 1, wn = wid & 1;
    const int lane16 = l & 15, lhi = l >> 4;
    const int m0 = blockIdx.x * 128;
    const int n0 = (MODE == 2 ? 2 * C : 0) + blockIdx.y * 128;

    const u16* Abase = Ab + (size_t)m0 * K_DIM;
    const u16* Bbase = Bb + (size_t)n0 * K_DIM;

    f32x4 acc[4][4] = {};

    for (int ks = 0; ks < K_DIM / 64; ++ks) {
        __syncthreads();                       // previous compute done, LDS free
        stage_g(As, Abase + ks * 64, K_DIM, tid);
        stage_g(Bs, Bbase + ks * 64, K_DIM, tid);
        __syncthreads();                       // drains vmcnt(0): tiles visible
        #pragma unroll
        for (int kc = 0; kc < 2; kc++) {
            bf16x8 af[4], bfr[4];
            #pragma unroll
            for (int mi = 0; mi < 4; mi++) {
                int row = wm * 64 + mi * 16 + lane16;
                int byte = row * 128 + kc * 64 + lhi * 16; byte ^= (row & 7) << 4;
                af[mi] = *(const bf16x8*)((const char*)As + byte);
            }
            #pragma unroll
            for (int ni = 0; ni < 4; ni++) {
                int row = wn * 64 + ni * 16 + lane16;
                int byte = row * 128 + kc * 64 + lhi * 16; byte ^= (row & 7) << 4;
                bfr[ni] = *(const bf16x8*)((const char*)Bs + byte);
            }
            #pragma unroll
            for (int mi = 0; mi < 4; mi++)
                #pragma unroll
                for (int ni = 0; ni < 4; ni++) {
                    if constexpr (MODE == 2)
                        acc[mi][ni] = __builtin_amdgcn_mfma_f32_16x16x32_bf16(
                            bfr[ni], af[mi], acc[mi][ni], 0, 0, 0);
                    else
                        acc[mi][ni] = __builtin_amdgcn_mfma_f32_16x16x32_bf16(
                            af[mi], bfr[ni], acc[mi][ni], 0, 0, 0);
                }
        }
    }

    if constexpr (MODE == 2) {
        // D layout: regs = W rows (out-features), lanes = x rows (t)
        #pragma unroll
        for (int mi = 0; mi < 4; mi++)
            #pragma unroll
            for (int ni = 0; ni < 4; ni++)
                #pragma unroll
                for (int r = 0; r < 4; r++) {
                    int wr = n0 + wn * 64 + ni * 16 + lhi * 4 + r;  // 2048..3071
                    int tg = m0 + wm * 64 + mi * 16 + lane16;       // 0..8191
                    int hh = (wr >> 6) & 15, d = wr & 63;
                    int bb = tg >> 11, tt = tg & 2047;
                    size_t off = (((size_t)bb * H + hh) * Dh + d) * T + tt;
                    vtws[off] = f2bf(acc[mi][ni][r]);
                }
    } else {
        #pragma unroll
        for (int mi = 0; mi < 4; mi++)
            #pragma unroll
            for (int ni = 0; ni < 4; ni++)
                #pragma unroll
                for (int r = 0; r < 4; r++) {
                    int gm = m0 + wm * 64 + mi * 16 + lhi * 4 + r;
                    int gn = n0 + wn * 64 + ni * 16 + lane16;
                    float val = acc[mi][ni][r];
                    if constexpr (MODE == 0) {
                        int hh = (gn >> 6) & 15, d = gn & 63;
                        int bb = gm >> 11, t = gm & 2047;
                        size_t off = (((size_t)bb * H + hh) * T + t) * Dh + d;
                        if (gn < C) qws[off] = f2bf(val * QSCALE);
                        else        kws[off] = f2bf(val);
                    } else {
                        Op[(size_t)gm * C + gn] = val;
                    }
                }
    }
}

// ---------------------------------------------------------------------------
// Flash attention, causal — swapped-QK 32x32 structure (m214 port).
// Block = 4 waves x 64 q-rows = 256 q-rows. KV tiles of 64, double-buffered
// LDS: K [64t][64d] and V^T [64d][64t], both XOR-swizzled via pre-swizzled
// global_load_lds source. Softmax fully in-register (P-row lane-local),
// P->bf16 A-frags via v_cvt_pk_bf16_f32 + v_permlane32_swap_b32.
// ---------------------------------------------------------------------------
__device__ inline bf16x8 ldsfrag(const u16* base, int row, int cc) {
    int byte = (row << 7) + (cc << 4); byte ^= (row & 7) << 4;
    return *(const bf16x8*)((const char*)base + byte);
}

// stage 64 rows x 128B, source chunk-swizzled so swizzled reads see row-major
__device__ inline void stage_t(u16* lds, const u16* gb, int rstride, int tid) {
    #pragma unroll
    for (int it = 0; it < 2; ++it) {
        int chunk = it * 256 + tid;
        int r = chunk >> 3, cc = chunk & 7;
        int sc = cc ^ (r & 7);
        g2l16(gb + (size_t)r * rstride + sc * 8, lds + (it * 256 + (tid & 192)) * 8);
    }
}

__global__ __launch_bounds__(256, 2)
void attn_k(const u16* __restrict__ qws, const u16* __restrict__ kws,
            const u16* __restrict__ vtws, u16* __restrict__ ows)
{
    __shared__ alignas(16) u16 KL[2][64 * 64];
    __shared__ alignas(16) u16 VL[2][64 * 64];

    const int bid = blockIdx.x;
    // complementary (long,short) pairing across the two residency rounds
    const int qt   = (bid < 256) ? 7 - (bid & 7) : (bid & 7);
    const int head = ((bid < 256) ? 0 : 32) + ((bid & 255) >> 3);
    const int b = head >> 4, h = head & 15;
    const int tid = threadIdx.x, w = tid >> 6, l = tid & 63;
    const int l31 = l & 31, hi = l >> 5;

    const size_t hoff = (size_t)head * (T * Dh);
    const u16* Qg  = qws + hoff;
    const u16* Kg  = kws + hoff;
    const u16* Vtg = vtws + hoff;   // [Dh][T] per head

    const int qb_w = qt * 256 + w * 64;
    const int nt = 4 * qt + 4;

    // Q fragments in registers (B-operand: row q = l&31, k = hi*8+j)
    bf16x8 qf[2][4];
    #pragma unroll
    for (int q2 = 0; q2 < 2; ++q2)
        #pragma unroll
        for (int c = 0; c < 4; ++c)
            qf[q2][c] = *(const bf16x8*)(Qg + (size_t)(qb_w + q2 * 32 + l31) * Dh
                                         + c * 16 + hi * 8);

    f32x16 o[2][2] = {};                       // [qblk][dblk]
    float mrun[2] = {-__builtin_inff(), -__builtin_inff()};
    float lrun[2] = {0.f, 0.f};

    stage_t(KL[0], Kg, Dh, tid);
    stage_t(VL[0], Vtg, T, tid);
    __syncthreads();

    for (int t = 0; t < nt; ++t) {
        const int cur = t & 1;
        if (t + 1 < nt) {
            stage_t(KL[cur ^ 1], Kg + (size_t)(t + 1) * 64 * Dh, Dh, tid);
            stage_t(VL[cur ^ 1], Vtg + (t + 1) * 64, T, tid);
        }
        const int kv0 = t * 64;
        if (kv0 <= qb_w + 63) {
            const u16* Kb = KL[cur];
            const u16* Vb = VL[cur];

            bf16x8 kf[2][4];   // A-operand: row kv = l&31 (+32*kvh), k = hi*8+j
            #pragma unroll
            for (int kvh = 0; kvh < 2; ++kvh)
                #pragma unroll
                for (int c = 0; c < 4; ++c)
                    kf[kvh][c] = ldsfrag(Kb, kvh * 32 + l31, c * 2 + hi);

            unsigned paf[2][4][4];
            const bool act0 = kv0 <= qb_w + 31;

            #pragma unroll
            for (int q2 = 0; q2 < 2; ++q2) {
                if (q2 == 0 && !act0) continue;
                f32x16 s0{}, s1{};
                #pragma unroll
                for (int c = 0; c < 4; ++c) {
                    s0 = __builtin_amdgcn_mfma_f32_32x32x16_bf16(kf[0][c], qf[q2][c], s0, 0, 0, 0);
                    s1 = __builtin_amdgcn_mfma_f32_32x32x16_bf16(kf[1][c], qf[q2][c], s1, 0, 0, 0);
                }
                const int qbb = qb_w + q2 * 32;
                if (kv0 + 63 > qbb) {          // diagonal: causal mask
                    int qg = qbb + l31;
                    #pragma unroll
                    for (int r = 0; r < 16; ++r) {
                        int kvg = kv0 + (r & 3) + 8 * (r >> 2) + 4 * hi;
                        if (kvg > qg)      s0[r] = -__builtin_inff();
                        if (kvg + 32 > qg) s1[r] = -__builtin_inff();
                    }
                }
                // ---- in-register online softmax (row q = l&31, pair lane l^32) ----
                float pmax = s0[0];
                #pragma unroll
                for (int r = 1; r < 16; ++r) pmax = fmaxf(pmax, s0[r]);
                #pragma unroll
                for (int r = 0; r < 16; ++r) pmax = fmaxf(pmax, s1[r]);
                pmax = fmaxf(pmax, __shfl_xor(pmax, 32));

                if (!__all(pmax - mrun[q2] <= 8.0f)) {   // T13 defer-max
                    float mn = fmaxf(mrun[q2], pmax);
                    float corr = __builtin_amdgcn_exp2f(mrun[q2] - mn);
                    mrun[q2] = mn;
                    lrun[q2] *= corr;
                    #pragma unroll
                    for (int r = 0; r < 16; ++r) {
                        float cr = __shfl(corr, (r & 3) + 8 * (r >> 2) + 4 * hi);
                        o[q2][0][r] *= cr;
                        o[q2][1][r] *= cr;
                    }
                }
                float p0[16], p1[16];
                #pragma unroll
                for (int r = 0; r < 16; ++r) {
                    p0[r] = __builtin_amdgcn_exp2f(s0[r] - mrun[q2]);
                    p1[r] = __builtin_amdgcn_exp2f(s1[r] - mrun[q2]);
                    lrun[q2] += p0[r] + p1[r];
                }
                // ---- P -> bf16 A-frags (T12: cvt_pk + permlane32_swap) ----
                unsigned cc[8];
                #pragma unroll
                for (int i = 0; i < 4; ++i) cc[i]     = pk2(p0[2 * i], p0[2 * i + 1]);
                #pragma unroll
                for (int i = 0; i < 4; ++i) cc[4 + i] = pk2(p0[8 + 2 * i], p0[9 + 2 * i]);
                swap32(cc[0], cc[2]); swap32(cc[1], cc[3]);
                swap32(cc[4], cc[6]); swap32(cc[5], cc[7]);
                #pragma unroll
                for (int i = 0; i < 4; ++i) { paf[q2][0][i] = cc[i]; paf[q2][1][i] = cc[4 + i]; }
                #pragma unroll
                for (int i = 0; i < 4; ++i) cc[i]     = pk2(p1[2 * i], p1[2 * i + 1]);
                #pragma unroll
                for (int i = 0; i < 4; ++i) cc[4 + i] = pk2(p1[8 + 2 * i], p1[9 + 2 * i]);
                swap32(cc[0], cc[2]); swap32(cc[1], cc[3]);
                swap32(cc[4], cc[6]); swap32(cc[5], cc[7]);
                #pragma unroll
                for (int i = 0; i < 4; ++i) { paf[q2][2][i] = cc[i]; paf[q2][3][i] = cc[4 + i]; }
            }

            bf16x8 vf[2][4];   // B-operand: row d = l&31 (+32*dblk), k = kv = hi*8+j
            #pragma unroll
            for (int db = 0; db < 2; ++db)
                #pragma unroll
                for (int kb = 0; kb < 4; ++kb)
                    vf[db][kb] = ldsfrag(Vb, db * 32 + l31, kb * 2 + hi);

            #pragma unroll
            for (int q2 = 0; q2 < 2; ++q2) {
                if (q2 == 0 && !act0) continue;
                #pragma unroll
                for (int db = 0; db < 2; ++db)
                    #pragma unroll
                    for (int kb = 0; kb < 4; ++kb) {
                        i32x4 wv = {(int)paf[q2][kb][0], (int)paf[q2][kb][1],
                                    (int)paf[q2][kb][2], (int)paf[q2][kb][3]};
                        o[q2][db] = __builtin_amdgcn_mfma_f32_32x32x16_bf16(
                            __builtin_bit_cast(bf16x8, wv), vf[db][kb], o[q2][db], 0, 0, 0);
                    }
            }
        }
        __syncthreads();
    }

    // ---- finalize ----
    #pragma unroll
    for (int q2 = 0; q2 < 2; ++q2) {
        float lt = lrun[q2] + __shfl_xor(lrun[q2], 32);
        float inv = 1.0f / lt;
        int qbb = qb_w + q2 * 32;
        #pragma unroll
        for (int r = 0; r < 16; ++r) {
            int cr = (r & 3) + 8 * (r >> 2) + 4 * hi;
            float il = __shfl(inv, cr);
            size_t rowoff = ((size_t)b * T + qbb + cr) * C + h * Dh + l31;
            ows[rowoff]      = f2bf(o[q2][0][r] * il);
            ows[rowoff + 32] = f2bf(o[q2][1][r] * il);
        }
    }
}

// ---------------------------------------------------------------------------
extern "C" void kernel_launch(void* const* d_in, const int* in_sizes, int n_in,
                              void* d_out, int out_size, void* d_ws, size_t ws_size,
                              hipStream_t stream)
{
    const float* x     = (const float*)d_in[0];
    const float* w_qkv = (const float*)d_in[1];
    const float* w_out = (const float*)d_in[2];
    float* out = (float*)d_out;

    const size_t SZ = (size_t)Bsz * H * T * Dh;  // 8388608 elems per tensor
    u16* qws   = (u16*)d_ws;
    u16* kws   = qws + SZ;
    u16* vtws  = kws + SZ;        // V transposed: [B][H][Dh][T]
    u16* xb    = vtws + SZ;       // x as bf16; ALIASED with ows (x consumed
    u16* ows   = xb;              //   by gemm0/gemm2 before attn writes ows)
    u16* wqkvb = xb + SZ;         // w_qkv bf16 (3072x1024)
    u16* woutb = wqkvb + (size_t)3 * C * C;  // w_out bf16 (1024x1024)

    cvt_k<<<dim3(6144), 256, 0, stream>>>(x, w_qkv, w_out, xb, wqkvb, woutb);

    dim3 gqk(Mrows / 128, (2 * C) / 128);
    gemm_k<0><<<gqk, 256, 0, stream>>>(xb, wqkvb, nullptr, qws, kws, vtws);
    dim3 gv(Mrows / 128, C / 128);
    gemm_k<2><<<gv, 256, 0, stream>>>(xb, wqkvb, nullptr, qws, kws, vtws);

    attn_k<<<dim3(512), 256, 0, stream>>>(qws, kws, vtws, ows);

    dim3 g1(Mrows / 128, C / 128);
    gemm_k<1><<<g1, 256, 0, stream>>>(ows, woutb, out, nullptr, nullptr, nullptr);
}

// Round 5
// 167.430 us; speedup vs baseline: 2.5894x; 1.0479x over previous
//
#include <hip/hip_runtime.h>

typedef __attribute__((ext_vector_type(8))) short bf16x8;
typedef __attribute__((ext_vector_type(4))) float f32x4;
typedef __attribute__((ext_vector_type(16))) float f32x16;
typedef __attribute__((ext_vector_type(4))) int i32x4;
using u16 = unsigned short;

constexpr int Bsz = 4, T = 2048, C = 1024, H = 16, Dh = 64;
constexpr int Mrows = Bsz * T;   // 8192
constexpr int K_DIM = 1024;
// scores = (q.k)/sqrt(64); softmax in exp2 domain -> fold (1/8)*log2(e) into Q
constexpr float QSCALE = 0.18033688011112042f;

__device__ inline u16 f2bf(float f) {
    unsigned u = __builtin_bit_cast(unsigned, f);
    u += 0x7FFFu + ((u >> 16) & 1u);
    return (u16)(u >> 16);
}

__device__ inline void g2l16(const void* g, void* l) {
    __builtin_amdgcn_global_load_lds((const __attribute__((address_space(1))) void*)g,
                                     (__attribute__((address_space(3))) void*)l, 16, 0, 0);
}

// pack 2 f32 -> 2 bf16 in one u32 (lo -> low half)
__device__ inline unsigned pk2(float lo, float hi) {
    unsigned d;
    asm("v_cvt_pk_bf16_f32 %0, %1, %2" : "=v"(d) : "v"(lo), "v"(hi));
    return d;
}
// a' = (a.lo32lanes, b.lo32lanes); b' = (a.hi32lanes, b.hi32lanes)
__device__ inline void swap32(unsigned& a, unsigned& b) {
    asm("v_permlane32_swap_b32 %0, %1" : "+v"(a), "+v"(b));
}

// ---------------------------------------------------------------------------
// One-shot f32 -> bf16 conversion of x, w_qkv, w_out (memory-bound, ~15us).
// Chunk = 8 elems. Ranges: x 1048576 chunks, w_qkv 393216, w_out 131072.
// ---------------------------------------------------------------------------
__global__ __launch_bounds__(256)
void cvt_k(const float* __restrict__ x, const float* __restrict__ wq,
           const float* __restrict__ wo, u16* __restrict__ xb,
           u16* __restrict__ wqb, u16* __restrict__ wob)
{
    int idx = blockIdx.x * 256 + threadIdx.x;
    const float* src; u16* dst; int rel;
    if (idx < 1048576)      { src = x;  dst = xb;  rel = idx; }
    else if (idx < 1441792) { src = wq; dst = wqb; rel = idx - 1048576; }
    else                    { src = wo; dst = wob; rel = idx - 1441792; }
    size_t off = (size_t)rel * 8;
    float4 a = *(const float4*)(src + off);
    float4 b = *(const float4*)(src + off + 4);
    unsigned r0 = (unsigned)f2bf(a.x) | ((unsigned)f2bf(a.y) << 16);
    unsigned r1 = (unsigned)f2bf(a.z) | ((unsigned)f2bf(a.w) << 16);
    unsigned r2 = (unsigned)f2bf(b.x) | ((unsigned)f2bf(b.y) << 16);
    unsigned r3 = (unsigned)f2bf(b.z) | ((unsigned)f2bf(b.w) << 16);
    *(uint4*)(dst + off) = make_uint4(r0, r1, r2, r3);
}

// ---------------------------------------------------------------------------
// m97-structure GEMM: C[M,N] = A[M,K] * B[N,K]^T, all-bf16 inputs.
// 128x128 tile, BK=64, 4 waves (2x2), global_load_lds dwordx4 staging with
// pre-swizzled global source (T2 both-sides), 2-barrier K-loop.
// MODE 0: -> Q,K bf16 (B,H,T,Dh), Q pre-scaled.   MODE 2: swapped mfma
// operands -> V^T (B,H,Dh,T).   MODE 1: bf16 attn-out -> f32 d_out.
// ---------------------------------------------------------------------------
__device__ inline void stage_g(u16* lds, const u16* gb, int ldg, int tid) {
    #pragma unroll
    for (int i = 0; i < 4; ++i) {
        int ch = i * 256 + tid;
        int r = ch >> 3, c8 = ch & 7;
        int sc = c8 ^ (r & 7);   // inverse-swizzled source, linear LDS dest
        g2l16(gb + (size_t)r * ldg + sc * 8, lds + (i * 256 + (tid & 192)) * 8);
    }
}

template<int MODE>
__global__ __launch_bounds__(256)
void gemm_k(const u16* __restrict__ Ab, const u16* __restrict__ Bb,
            float* __restrict__ Op, u16* __restrict__ qws,
            u16* __restrict__ kws, u16* __restrict__ vtws)
{
    __shared__ alignas(16) u16 As[128 * 64];
    __shared__ alignas(16) u16 Bs[128 * 64];
    const int tid = threadIdx.x;
    const int l = tid & 63, wid = tid >> 6;
    const int wm = wid >> 1, wn = wid & 1;
    const int lane16 = l & 15, lhi = l >> 4;
    const int m0 = blockIdx.x * 128;
    const int n0 = (MODE == 2 ? 2 * C : 0) + blockIdx.y * 128;

    const u16* Abase = Ab + (size_t)m0 * K_DIM;
    const u16* Bbase = Bb + (size_t)n0 * K_DIM;

    f32x4 acc[4][4] = {};

    for (int ks = 0; ks < K_DIM / 64; ++ks) {
        __syncthreads();                       // previous compute done, LDS free
        stage_g(As, Abase + ks * 64, K_DIM, tid);
        stage_g(Bs, Bbase + ks * 64, K_DIM, tid);
        __syncthreads();                       // drains vmcnt(0): tiles visible
        #pragma unroll
        for (int kc = 0; kc < 2; kc++) {
            bf16x8 af[4], bfr[4];
            #pragma unroll
            for (int mi = 0; mi < 4; mi++) {
                int row = wm * 64 + mi * 16 + lane16;
                int byte = row * 128 + kc * 64 + lhi * 16; byte ^= (row & 7) << 4;
                af[mi] = *(const bf16x8*)((const char*)As + byte);
            }
            #pragma unroll
            for (int ni = 0; ni < 4; ni++) {
                int row = wn * 64 + ni * 16 + lane16;
                int byte = row * 128 + kc * 64 + lhi * 16; byte ^= (row & 7) << 4;
                bfr[ni] = *(const bf16x8*)((const char*)Bs + byte);
            }
            #pragma unroll
            for (int mi = 0; mi < 4; mi++)
                #pragma unroll
                for (int ni = 0; ni < 4; ni++) {
                    if constexpr (MODE == 2)
                        acc[mi][ni] = __builtin_amdgcn_mfma_f32_16x16x32_bf16(
                            bfr[ni], af[mi], acc[mi][ni], 0, 0, 0);
                    else
                        acc[mi][ni] = __builtin_amdgcn_mfma_f32_16x16x32_bf16(
                            af[mi], bfr[ni], acc[mi][ni], 0, 0, 0);
                }
        }
    }

    if constexpr (MODE == 2) {
        // D layout: regs = W rows (out-features), lanes = x rows (t)
        #pragma unroll
        for (int mi = 0; mi < 4; mi++)
            #pragma unroll
            for (int ni = 0; ni < 4; ni++)
                #pragma unroll
                for (int r = 0; r < 4; r++) {
                    int wr = n0 + wn * 64 + ni * 16 + lhi * 4 + r;  // 2048..3071
                    int tg = m0 + wm * 64 + mi * 16 + lane16;       // 0..8191
                    int hh = (wr >> 6) & 15, d = wr & 63;
                    int bb = tg >> 11, tt = tg & 2047;
                    size_t off = (((size_t)bb * H + hh) * Dh + d) * T + tt;
                    vtws[off] = f2bf(acc[mi][ni][r]);
                }
    } else {
        #pragma unroll
        for (int mi = 0; mi < 4; mi++)
            #pragma unroll
            for (int ni = 0; ni < 4; ni++)
                #pragma unroll
                for (int r = 0; r < 4; r++) {
                    int gm = m0 + wm * 64 + mi * 16 + lhi * 4 + r;
                    int gn = n0 + wn * 64 + ni * 16 + lane16;
                    float val = acc[mi][ni][r];
                    if constexpr (MODE == 0) {
                        int hh = (gn >> 6) & 15, d = gn & 63;
                        int bb = gm >> 11, t = gm & 2047;
                        size_t off = (((size_t)bb * H + hh) * T + t) * Dh + d;
                        if (gn < C) qws[off] = f2bf(val * QSCALE);
                        else        kws[off] = f2bf(val);
                    } else {
                        Op[(size_t)gm * C + gn] = val;
                    }
                }
    }
}

// ---------------------------------------------------------------------------
// Flash attention, causal — swapped-QK 32x32, balance-by-construction.
// Block = (head, p): processes 128-row q-tiles qt=p and qt=15-p, so EVERY
// block costs exactly (2p+2)+(2(15-p)+2) = 34 kv-tile steps regardless of
// dispatcher placement (round-4 fix: pairing via bid assumed placement and
// hit 60-step CUs). 4 waves x 32 q-rows per tile; K/V tiles of 64 double-
// buffered in LDS (K [64t][64d], V^T [64d][64t], XOR-swizzled both-sides).
// Softmax fully in-register; P->bf16 via cvt_pk + permlane32_swap.
// ---------------------------------------------------------------------------
__device__ inline bf16x8 ldsfrag(const u16* base, int row, int cc) {
    int byte = (row << 7) + (cc << 4); byte ^= (row & 7) << 4;
    return *(const bf16x8*)((const char*)base + byte);
}

// stage 64 rows x 128B, source chunk-swizzled so swizzled reads see row-major
__device__ inline void stage_t(u16* lds, const u16* gb, int rstride, int tid) {
    #pragma unroll
    for (int it = 0; it < 2; ++it) {
        int chunk = it * 256 + tid;
        int r = chunk >> 3, cc = chunk & 7;
        int sc = cc ^ (r & 7);
        g2l16(gb + (size_t)r * rstride + sc * 8, lds + (it * 256 + (tid & 192)) * 8);
    }
}

__global__ __launch_bounds__(256, 2)
void attn_k(const u16* __restrict__ qws, const u16* __restrict__ kws,
            const u16* __restrict__ vtws, u16* __restrict__ ows)
{
    __shared__ alignas(16) u16 KL[2][64 * 64];
    __shared__ alignas(16) u16 VL[2][64 * 64];

    const int bid = blockIdx.x;
    const int p = bid & 7;                // tile pair (p, 15-p): constant cost
    const int head = bid >> 3;
    const int b = head >> 4, h = head & 15;
    const int tid = threadIdx.x, w = tid >> 6, l = tid & 63;
    const int l31 = l & 31, hi = l >> 5;

    const size_t hoff = (size_t)head * (T * Dh);
    const u16* Qg  = qws + hoff;
    const u16* Kg  = kws + hoff;
    const u16* Vtg = vtws + hoff;   // [Dh][T] per head

    #pragma unroll
    for (int half = 0; half < 2; ++half) {
        const int qt = half ? 15 - p : p;     // 128-row q tile
        const int qb = qt * 128;
        const int nt = 2 * qt + 2;
        const int qbw = qb + w * 32;          // this wave's 32 q rows

        // Q fragments (B-operand: row q = l&31, k = hi*8+j)
        bf16x8 qf[4];
        #pragma unroll
        for (int c = 0; c < 4; ++c)
            qf[c] = *(const bf16x8*)(Qg + (size_t)(qbw + l31) * Dh + c * 16 + hi * 8);

        f32x16 o0{}, o1{};                    // d 0..31 / 32..63
        float mrun = -__builtin_inff(), lrun = 0.f;

        stage_t(KL[0], Kg, Dh, tid);
        stage_t(VL[0], Vtg, T, tid);
        __syncthreads();

        for (int t = 0; t < nt; ++t) {
            const int cur = t & 1;
            if (t + 1 < nt) {
                stage_t(KL[cur ^ 1], Kg + (size_t)(t + 1) * 64 * Dh, Dh, tid);
                stage_t(VL[cur ^ 1], Vtg + (t + 1) * 64, T, tid);
            }
            const int kv0 = t * 64;
            if (kv0 <= qbw + 31) {            // wave has unmasked work
                const u16* Kb = KL[cur];
                const u16* Vb = VL[cur];

                bf16x8 kf0[4], kf1[4];        // A-operand: kv rows 0..31 / 32..63
                #pragma unroll
                for (int c = 0; c < 4; ++c) {
                    kf0[c] = ldsfrag(Kb, l31, c * 2 + hi);
                    kf1[c] = ldsfrag(Kb, 32 + l31, c * 2 + hi);
                }

                f32x16 s0{}, s1{};
                #pragma unroll
                for (int c = 0; c < 4; ++c) {
                    s0 = __builtin_amdgcn_mfma_f32_32x32x16_bf16(kf0[c], qf[c], s0, 0, 0, 0);
                    s1 = __builtin_amdgcn_mfma_f32_32x32x16_bf16(kf1[c], qf[c], s1, 0, 0, 0);
                }

                if (kv0 + 63 > qbw) {         // diagonal: causal mask
                    int qg = qbw + l31;
                    #pragma unroll
                    for (int r = 0; r < 16; ++r) {
                        int kvg = kv0 + (r & 3) + 8 * (r >> 2) + 4 * hi;
                        if (kvg > qg)      s0[r] = -__builtin_inff();
                        if (kvg + 32 > qg) s1[r] = -__builtin_inff();
                    }
                }

                // ---- in-register online softmax (row q = l&31; pair l^32) ----
                float m16[16];
                #pragma unroll
                for (int r = 0; r < 16; ++r) m16[r] = fmaxf(s0[r], s1[r]);
                #pragma unroll
                for (int d = 8; d; d >>= 1)
                    #pragma unroll
                    for (int r = 0; r < d; ++r) m16[r] = fmaxf(m16[r], m16[r + d]);
                float pmax = fmaxf(m16[0], __shfl_xor(m16[0], 32));

                if (!__all(pmax - mrun <= 8.0f)) {   // T13 defer-max
                    float mn = fmaxf(mrun, pmax);
                    float corr = __builtin_amdgcn_exp2f(mrun - mn);
                    mrun = mn;
                    lrun *= corr;
                    #pragma unroll
                    for (int r = 0; r < 16; ++r) {
                        float cr = __shfl(corr, (r & 3) + 8 * (r >> 2) + 4 * hi);
                        o0[r] *= cr;
                        o1[r] *= cr;
                    }
                }
                float p0[16], p1[16];
                float t0 = 0.f, t1 = 0.f, t2 = 0.f, t3 = 0.f;
                #pragma unroll
                for (int r = 0; r < 16; ++r) {
                    p0[r] = __builtin_amdgcn_exp2f(s0[r] - mrun);
                    p1[r] = __builtin_amdgcn_exp2f(s1[r] - mrun);
                    float s = p0[r] + p1[r];
                    if ((r & 3) == 0) t0 += s; else if ((r & 3) == 1) t1 += s;
                    else if ((r & 3) == 2) t2 += s; else t3 += s;
                }
                lrun += (t0 + t1) + (t2 + t3);

                // ---- P -> bf16 A-frags (T12: cvt_pk + permlane32_swap) ----
                unsigned paf[4][4];
                unsigned cc[8];
                #pragma unroll
                for (int i = 0; i < 4; ++i) cc[i]     = pk2(p0[2 * i], p0[2 * i + 1]);
                #pragma unroll
                for (int i = 0; i < 4; ++i) cc[4 + i] = pk2(p0[8 + 2 * i], p0[9 + 2 * i]);
                swap32(cc[0], cc[2]); swap32(cc[1], cc[3]);
                swap32(cc[4], cc[6]); swap32(cc[5], cc[7]);
                #pragma unroll
                for (int i = 0; i < 4; ++i) { paf[0][i] = cc[i]; paf[1][i] = cc[4 + i]; }
                #pragma unroll
                for (int i = 0; i < 4; ++i) cc[i]     = pk2(p1[2 * i], p1[2 * i + 1]);
                #pragma unroll
                for (int i = 0; i < 4; ++i) cc[4 + i] = pk2(p1[8 + 2 * i], p1[9 + 2 * i]);
                swap32(cc[0], cc[2]); swap32(cc[1], cc[3]);
                swap32(cc[4], cc[6]); swap32(cc[5], cc[7]);
                #pragma unroll
                for (int i = 0; i < 4; ++i) { paf[2][i] = cc[i]; paf[3][i] = cc[4 + i]; }

                // ---- O += P V ----
                #pragma unroll
                for (int kb = 0; kb < 4; ++kb) {
                    i32x4 wv = {(int)paf[kb][0], (int)paf[kb][1],
                                (int)paf[kb][2], (int)paf[kb][3]};
                    bf16x8 pa = __builtin_bit_cast(bf16x8, wv);
                    bf16x8 v0 = ldsfrag(Vb, l31,      kb * 2 + hi);
                    bf16x8 v1 = ldsfrag(Vb, 32 + l31, kb * 2 + hi);
                    o0 = __builtin_amdgcn_mfma_f32_32x32x16_bf16(pa, v0, o0, 0, 0, 0);
                    o1 = __builtin_amdgcn_mfma_f32_32x32x16_bf16(pa, v1, o1, 0, 0, 0);
                }
            }
            __syncthreads();
        }

        // ---- finalize ----
        float lt = lrun + __shfl_xor(lrun, 32);
        float inv = 1.0f / lt;
        #pragma unroll
        for (int r = 0; r < 16; ++r) {
            int cr = (r & 3) + 8 * (r >> 2) + 4 * hi;
            float il = __shfl(inv, cr);
            size_t rowoff = ((size_t)b * T + qb + w * 32 + cr) * C + h * Dh + l31;
            ows[rowoff]      = f2bf(o0[r] * il);
            ows[rowoff + 32] = f2bf(o1[r] * il);
        }
    }
}

// ---------------------------------------------------------------------------
extern "C" void kernel_launch(void* const* d_in, const int* in_sizes, int n_in,
                              void* d_out, int out_size, void* d_ws, size_t ws_size,
                              hipStream_t stream)
{
    const float* x     = (const float*)d_in[0];
    const float* w_qkv = (const float*)d_in[1];
    const float* w_out = (const float*)d_in[2];
    float* out = (float*)d_out;

    const size_t SZ = (size_t)Bsz * H * T * Dh;  // 8388608 elems per tensor
    u16* qws   = (u16*)d_ws;
    u16* kws   = qws + SZ;
    u16* vtws  = kws + SZ;        // V transposed: [B][H][Dh][T]
    u16* xb    = vtws + SZ;       // x as bf16; ALIASED with ows (x consumed
    u16* ows   = xb;              //   by gemm0/gemm2 before attn writes ows)
    u16* wqkvb = xb + SZ;         // w_qkv bf16 (3072x1024)
    u16* woutb = wqkvb + (size_t)3 * C * C;  // w_out bf16 (1024x1024)

    cvt_k<<<dim3(6144), 256, 0, stream>>>(x, w_qkv, w_out, xb, wqkvb, woutb);

    dim3 gqk(Mrows / 128, (2 * C) / 128);
    gemm_k<0><<<gqk, 256, 0, stream>>>(xb, wqkvb, nullptr, qws, kws, vtws);
    dim3 gv(Mrows / 128, C / 128);
    gemm_k<2><<<gv, 256, 0, stream>>>(xb, wqkvb, nullptr, qws, kws, vtws);

    attn_k<<<dim3(512), 256, 0, stream>>>(qws, kws, vtws, ows);

    dim3 g1(Mrows / 128, C / 128);
    gemm_k<1><<<g1, 256, 0, stream>>>(ows, woutb, out, nullptr, nullptr, nullptr);
}

// Round 6
// 162.840 us; speedup vs baseline: 2.6623x; 1.0282x over previous
//
#include <hip/hip_runtime.h>

typedef __attribute__((ext_vector_type(8))) short bf16x8;
typedef __attribute__((ext_vector_type(4))) float f32x4;
typedef __attribute__((ext_vector_type(16))) float f32x16;
typedef __attribute__((ext_vector_type(4))) int i32x4;
using u16 = unsigned short;

constexpr int Bsz = 4, T = 2048, C = 1024, H = 16, Dh = 64;
constexpr int Mrows = Bsz * T;   // 8192
constexpr int K_DIM = 1024;
// scores = (q.k)/sqrt(64); softmax in exp2 domain -> fold (1/8)*log2(e) into Q
constexpr float QSCALE = 0.18033688011112042f;

__device__ inline u16 f2bf(float f) {
    unsigned u = __builtin_bit_cast(unsigned, f);
    u += 0x7FFFu + ((u >> 16) & 1u);
    return (u16)(u >> 16);
}

__device__ inline void g2l16(const void* g, void* l) {
    __builtin_amdgcn_global_load_lds((const __attribute__((address_space(1))) void*)g,
                                     (__attribute__((address_space(3))) void*)l, 16, 0, 0);
}

// pack 2 f32 -> 2 bf16 in one u32 (lo -> low half)
__device__ inline unsigned pk2(float lo, float hi) {
    unsigned d;
    asm("v_cvt_pk_bf16_f32 %0, %1, %2" : "=v"(d) : "v"(lo), "v"(hi));
    return d;
}
// a' = (a.lo32lanes, b.lo32lanes); b' = (a.hi32lanes, b.hi32lanes)
__device__ inline void swap32(unsigned& a, unsigned& b) {
    asm("v_permlane32_swap_b32 %0, %1" : "+v"(a), "+v"(b));
}

// ---------------------------------------------------------------------------
// One-shot f32 -> bf16 conversion of x, w_qkv, w_out (memory-bound, ~15us).
// Chunk = 8 elems. Ranges: x 1048576 chunks, w_qkv 393216, w_out 131072.
// ---------------------------------------------------------------------------
__global__ __launch_bounds__(256)
void cvt_k(const float* __restrict__ x, const float* __restrict__ wq,
           const float* __restrict__ wo, u16* __restrict__ xb,
           u16* __restrict__ wqb, u16* __restrict__ wob)
{
    int idx = blockIdx.x * 256 + threadIdx.x;
    const float* src; u16* dst; int rel;
    if (idx < 1048576)      { src = x;  dst = xb;  rel = idx; }
    else if (idx < 1441792) { src = wq; dst = wqb; rel = idx - 1048576; }
    else                    { src = wo; dst = wob; rel = idx - 1441792; }
    size_t off = (size_t)rel * 8;
    float4 a = *(const float4*)(src + off);
    float4 b = *(const float4*)(src + off + 4);
    unsigned r0 = (unsigned)f2bf(a.x) | ((unsigned)f2bf(a.y) << 16);
    unsigned r1 = (unsigned)f2bf(a.z) | ((unsigned)f2bf(a.w) << 16);
    unsigned r2 = (unsigned)f2bf(b.x) | ((unsigned)f2bf(b.y) << 16);
    unsigned r3 = (unsigned)f2bf(b.z) | ((unsigned)f2bf(b.w) << 16);
    *(uint4*)(dst + off) = make_uint4(r0, r1, r2, r3);
}

// ---------------------------------------------------------------------------
// m97-structure GEMM: C[M,N] = A[M,K] * B[N,K]^T, all-bf16 inputs.
// 128x128 tile, BK=64, 4 waves (2x2), global_load_lds dwordx4 staging with
// pre-swizzled global source (T2 both-sides), 2-barrier K-loop.
// MODE 0: -> Q,K bf16 (B,H,T,Dh), Q pre-scaled.   MODE 2: swapped mfma
// operands -> V^T (B,H,Dh,T).   MODE 1: bf16 attn-out -> f32 d_out.
// ---------------------------------------------------------------------------
__device__ inline void stage_g(u16* lds, const u16* gb, int ldg, int tid) {
    #pragma unroll
    for (int i = 0; i < 4; ++i) {
        int ch = i * 256 + tid;
        int r = ch >> 3, c8 = ch & 7;
        int sc = c8 ^ (r & 7);   // inverse-swizzled source, linear LDS dest
        g2l16(gb + (size_t)r * ldg + sc * 8, lds + (i * 256 + (tid & 192)) * 8);
    }
}

template<int MODE>
__global__ __launch_bounds__(256)
void gemm_k(const u16* __restrict__ Ab, const u16* __restrict__ Bb,
            float* __restrict__ Op, u16* __restrict__ qws,
            u16* __restrict__ kws, u16* __restrict__ vtws)
{
    __shared__ alignas(16) u16 As[128 * 64];
    __shared__ alignas(16) u16 Bs[128 * 64];
    const int tid = threadIdx.x;
    const int l = tid & 63, wid = tid >> 6;
    const int wm = wid >> 1, wn = wid & 1;
    const int lane16 = l & 15, lhi = l >> 4;
    const int m0 = blockIdx.x * 128;
    const int n0 = (MODE == 2 ? 2 * C : 0) + blockIdx.y * 128;

    const u16* Abase = Ab + (size_t)m0 * K_DIM;
    const u16* Bbase = Bb + (size_t)n0 * K_DIM;

    f32x4 acc[4][4] = {};

    for (int ks = 0; ks < K_DIM / 64; ++ks) {
        __syncthreads();                       // previous compute done, LDS free
        stage_g(As, Abase + ks * 64, K_DIM, tid);
        stage_g(Bs, Bbase + ks * 64, K_DIM, tid);
        __syncthreads();                       // drains vmcnt(0): tiles visible
        #pragma unroll
        for (int kc = 0; kc < 2; kc++) {
            bf16x8 af[4], bfr[4];
            #pragma unroll
            for (int mi = 0; mi < 4; mi++) {
                int row = wm * 64 + mi * 16 + lane16;
                int byte = row * 128 + kc * 64 + lhi * 16; byte ^= (row & 7) << 4;
                af[mi] = *(const bf16x8*)((const char*)As + byte);
            }
            #pragma unroll
            for (int ni = 0; ni < 4; ni++) {
                int row = wn * 64 + ni * 16 + lane16;
                int byte = row * 128 + kc * 64 + lhi * 16; byte ^= (row & 7) << 4;
                bfr[ni] = *(const bf16x8*)((const char*)Bs + byte);
            }
            #pragma unroll
            for (int mi = 0; mi < 4; mi++)
                #pragma unroll
                for (int ni = 0; ni < 4; ni++) {
                    if constexpr (MODE == 2)
                        acc[mi][ni] = __builtin_amdgcn_mfma_f32_16x16x32_bf16(
                            bfr[ni], af[mi], acc[mi][ni], 0, 0, 0);
                    else
                        acc[mi][ni] = __builtin_amdgcn_mfma_f32_16x16x32_bf16(
                            af[mi], bfr[ni], acc[mi][ni], 0, 0, 0);
                }
        }
    }

    if constexpr (MODE == 2) {
        // D layout: regs = W rows (out-features), lanes = x rows (t)
        #pragma unroll
        for (int mi = 0; mi < 4; mi++)
            #pragma unroll
            for (int ni = 0; ni < 4; ni++)
                #pragma unroll
                for (int r = 0; r < 4; r++) {
                    int wr = n0 + wn * 64 + ni * 16 + lhi * 4 + r;  // 2048..3071
                    int tg = m0 + wm * 64 + mi * 16 + lane16;       // 0..8191
                    int hh = (wr >> 6) & 15, d = wr & 63;
                    int bb = tg >> 11, tt = tg & 2047;
                    size_t off = (((size_t)bb * H + hh) * Dh + d) * T + tt;
                    vtws[off] = f2bf(acc[mi][ni][r]);
                }
    } else {
        #pragma unroll
        for (int mi = 0; mi < 4; mi++)
            #pragma unroll
            for (int ni = 0; ni < 4; ni++)
                #pragma unroll
                for (int r = 0; r < 4; r++) {
                    int gm = m0 + wm * 64 + mi * 16 + lhi * 4 + r;
                    int gn = n0 + wn * 64 + ni * 16 + lane16;
                    float val = acc[mi][ni][r];
                    if constexpr (MODE == 0) {
                        int hh = (gn >> 6) & 15, d = gn & 63;
                        int bb = gm >> 11, t = gm & 2047;
                        size_t off = (((size_t)bb * H + hh) * T + t) * Dh + d;
                        if (gn < C) qws[off] = f2bf(val * QSCALE);
                        else        kws[off] = f2bf(val);
                    } else {
                        Op[(size_t)gm * C + gn] = val;
                    }
                }
    }
}

// ---------------------------------------------------------------------------
// Flash attention, causal — swapped-QK 32x32.
// Round-6 structure: ONE 128-row q-tile per block, grid = 1024 = 4 blocks/CU
// (16 waves/CU, 2x round-5) -> latency hiding via TLP; balance via greedy
// dispatcher refill + longest-tile-first ordering (qt = 15 - bid/64).
// head = bid & 63 => XCD = bid%8 = head%8: all 16 tiles of a head share one
// XCD's L2 (8 heads x 512 KB KV = 4 MB = one L2) -> KV re-reads become L2
// hits instead of the round-5 147 MB HBM fetch.
// K/V tiles of 64 double-buffered in LDS, XOR-swizzled both-sides.
// Softmax fully in-register; P->bf16 via cvt_pk + permlane32_swap.
// ---------------------------------------------------------------------------
__device__ inline bf16x8 ldsfrag(const u16* base, int row, int cc) {
    int byte = (row << 7) + (cc << 4); byte ^= (row & 7) << 4;
    return *(const bf16x8*)((const char*)base + byte);
}

// stage 64 rows x 128B, source chunk-swizzled so swizzled reads see row-major
__device__ inline void stage_t(u16* lds, const u16* gb, int rstride, int tid) {
    #pragma unroll
    for (int it = 0; it < 2; ++it) {
        int chunk = it * 256 + tid;
        int r = chunk >> 3, cc = chunk & 7;
        int sc = cc ^ (r & 7);
        g2l16(gb + (size_t)r * rstride + sc * 8, lds + (it * 256 + (tid & 192)) * 8);
    }
}

__global__ __launch_bounds__(256, 4)
void attn_k(const u16* __restrict__ qws, const u16* __restrict__ kws,
            const u16* __restrict__ vtws, u16* __restrict__ ows)
{
    __shared__ alignas(16) u16 KL[2][64 * 64];
    __shared__ alignas(16) u16 VL[2][64 * 64];

    const int bid = blockIdx.x;
    const int head = bid & 63;            // XCD = bid%8 = head%8 (L2 locality)
    const int qt = 15 - (bid >> 6);       // longest q-tiles dispatched first
    const int b = head >> 4, h = head & 15;
    const int tid = threadIdx.x, w = tid >> 6, l = tid & 63;
    const int l31 = l & 31, hi = l >> 5;

    const size_t hoff = (size_t)head * (T * Dh);
    const u16* Qg  = qws + hoff;
    const u16* Kg  = kws + hoff;
    const u16* Vtg = vtws + hoff;   // [Dh][T] per head

    const int qb = qt * 128;
    const int nt = 2 * qt + 2;
    const int qbw = qb + w * 32;          // this wave's 32 q rows

    // Q fragments (B-operand: row q = l&31, k = hi*8+j)
    bf16x8 qf[4];
    #pragma unroll
    for (int c = 0; c < 4; ++c)
        qf[c] = *(const bf16x8*)(Qg + (size_t)(qbw + l31) * Dh + c * 16 + hi * 8);

    f32x16 o0{}, o1{};                    // d 0..31 / 32..63
    float mrun = -__builtin_inff(), lrun = 0.f;

    stage_t(KL[0], Kg, Dh, tid);
    stage_t(VL[0], Vtg, T, tid);
    __syncthreads();

    for (int t = 0; t < nt; ++t) {
        const int cur = t & 1;
        if (t + 1 < nt) {
            stage_t(KL[cur ^ 1], Kg + (size_t)(t + 1) * 64 * Dh, Dh, tid);
            stage_t(VL[cur ^ 1], Vtg + (t + 1) * 64, T, tid);
        }
        const int kv0 = t * 64;
        if (kv0 <= qbw + 31) {            // wave has unmasked work
            const u16* Kb = KL[cur];
            const u16* Vb = VL[cur];

            bf16x8 kf0[4], kf1[4];        // A-operand: kv rows 0..31 / 32..63
            #pragma unroll
            for (int c = 0; c < 4; ++c) {
                kf0[c] = ldsfrag(Kb, l31, c * 2 + hi);
                kf1[c] = ldsfrag(Kb, 32 + l31, c * 2 + hi);
            }

            f32x16 s0{}, s1{};
            #pragma unroll
            for (int c = 0; c < 4; ++c) {
                s0 = __builtin_amdgcn_mfma_f32_32x32x16_bf16(kf0[c], qf[c], s0, 0, 0, 0);
                s1 = __builtin_amdgcn_mfma_f32_32x32x16_bf16(kf1[c], qf[c], s1, 0, 0, 0);
            }

            if (kv0 + 63 > qbw) {         // diagonal: causal mask
                int qg = qbw + l31;
                #pragma unroll
                for (int r = 0; r < 16; ++r) {
                    int kvg = kv0 + (r & 3) + 8 * (r >> 2) + 4 * hi;
                    if (kvg > qg)      s0[r] = -__builtin_inff();
                    if (kvg + 32 > qg) s1[r] = -__builtin_inff();
                }
            }

            // ---- in-register online softmax (row q = l&31; pair l^32) ----
            float m16[16];
            #pragma unroll
            for (int r = 0; r < 16; ++r) m16[r] = fmaxf(s0[r], s1[r]);
            #pragma unroll
            for (int d = 8; d; d >>= 1)
                #pragma unroll
                for (int r = 0; r < d; ++r) m16[r] = fmaxf(m16[r], m16[r + d]);
            float pmax = fmaxf(m16[0], __shfl_xor(m16[0], 32));

            if (!__all(pmax - mrun <= 8.0f)) {   // T13 defer-max
                float mn = fmaxf(mrun, pmax);
                float corr = __builtin_amdgcn_exp2f(mrun - mn);
                mrun = mn;
                lrun *= corr;
                #pragma unroll
                for (int r = 0; r < 16; ++r) {
                    float cr = __shfl(corr, (r & 3) + 8 * (r >> 2) + 4 * hi);
                    o0[r] *= cr;
                    o1[r] *= cr;
                }
            }
            float p0[16], p1[16];
            float t0 = 0.f, t1 = 0.f, t2 = 0.f, t3 = 0.f;
            #pragma unroll
            for (int r = 0; r < 16; ++r) {
                p0[r] = __builtin_amdgcn_exp2f(s0[r] - mrun);
                p1[r] = __builtin_amdgcn_exp2f(s1[r] - mrun);
                float s = p0[r] + p1[r];
                if ((r & 3) == 0) t0 += s; else if ((r & 3) == 1) t1 += s;
                else if ((r & 3) == 2) t2 += s; else t3 += s;
            }
            lrun += (t0 + t1) + (t2 + t3);

            // ---- P -> bf16 A-frags (T12: cvt_pk + permlane32_swap) ----
            unsigned paf[4][4];
            unsigned cc[8];
            #pragma unroll
            for (int i = 0; i < 4; ++i) cc[i]     = pk2(p0[2 * i], p0[2 * i + 1]);
            #pragma unroll
            for (int i = 0; i < 4; ++i) cc[4 + i] = pk2(p0[8 + 2 * i], p0[9 + 2 * i]);
            swap32(cc[0], cc[2]); swap32(cc[1], cc[3]);
            swap32(cc[4], cc[6]); swap32(cc[5], cc[7]);
            #pragma unroll
            for (int i = 0; i < 4; ++i) { paf[0][i] = cc[i]; paf[1][i] = cc[4 + i]; }
            #pragma unroll
            for (int i = 0; i < 4; ++i) cc[i]     = pk2(p1[2 * i], p1[2 * i + 1]);
            #pragma unroll
            for (int i = 0; i < 4; ++i) cc[4 + i] = pk2(p1[8 + 2 * i], p1[9 + 2 * i]);
            swap32(cc[0], cc[2]); swap32(cc[1], cc[3]);
            swap32(cc[4], cc[6]); swap32(cc[5], cc[7]);
            #pragma unroll
            for (int i = 0; i < 4; ++i) { paf[2][i] = cc[i]; paf[3][i] = cc[4 + i]; }

            // ---- O += P V ----
            #pragma unroll
            for (int kb = 0; kb < 4; ++kb) {
                i32x4 wv = {(int)paf[kb][0], (int)paf[kb][1],
                            (int)paf[kb][2], (int)paf[kb][3]};
                bf16x8 pa = __builtin_bit_cast(bf16x8, wv);
                bf16x8 v0 = ldsfrag(Vb, l31,      kb * 2 + hi);
                bf16x8 v1 = ldsfrag(Vb, 32 + l31, kb * 2 + hi);
                o0 = __builtin_amdgcn_mfma_f32_32x32x16_bf16(pa, v0, o0, 0, 0, 0);
                o1 = __builtin_amdgcn_mfma_f32_32x32x16_bf16(pa, v1, o1, 0, 0, 0);
            }
        }
        __syncthreads();
    }

    // ---- finalize ----
    float lt = lrun + __shfl_xor(lrun, 32);
    float inv = 1.0f / lt;
    #pragma unroll
    for (int r = 0; r < 16; ++r) {
        int cr = (r & 3) + 8 * (r >> 2) + 4 * hi;
        float il = __shfl(inv, cr);
        size_t rowoff = ((size_t)b * T + qb + w * 32 + cr) * C + h * Dh + l31;
        ows[rowoff]      = f2bf(o0[r] * il);
        ows[rowoff + 32] = f2bf(o1[r] * il);
    }
}

// ---------------------------------------------------------------------------
extern "C" void kernel_launch(void* const* d_in, const int* in_sizes, int n_in,
                              void* d_out, int out_size, void* d_ws, size_t ws_size,
                              hipStream_t stream)
{
    const float* x     = (const float*)d_in[0];
    const float* w_qkv = (const float*)d_in[1];
    const float* w_out = (const float*)d_in[2];
    float* out = (float*)d_out;

    const size_t SZ = (size_t)Bsz * H * T * Dh;  // 8388608 elems per tensor
    u16* qws   = (u16*)d_ws;
    u16* kws   = qws + SZ;
    u16* vtws  = kws + SZ;        // V transposed: [B][H][Dh][T]
    u16* xb    = vtws + SZ;       // x as bf16; ALIASED with ows (x consumed
    u16* ows   = xb;              //   by gemm0/gemm2 before attn writes ows)
    u16* wqkvb = xb + SZ;         // w_qkv bf16 (3072x1024)
    u16* woutb = wqkvb + (size_t)3 * C * C;  // w_out bf16 (1024x1024)

    cvt_k<<<dim3(6144), 256, 0, stream>>>(x, w_qkv, w_out, xb, wqkvb, woutb);

    dim3 gqk(Mrows / 128, (2 * C) / 128);
    gemm_k<0><<<gqk, 256, 0, stream>>>(xb, wqkvb, nullptr, qws, kws, vtws);
    dim3 gv(Mrows / 128, C / 128);
    gemm_k<2><<<gv, 256, 0, stream>>>(xb, wqkvb, nullptr, qws, kws, vtws);

    attn_k<<<dim3(1024), 256, 0, stream>>>(qws, kws, vtws, ows);

    dim3 g1(Mrows / 128, C / 128);
    gemm_k<1><<<g1, 256, 0, stream>>>(ows, woutb, out, nullptr, nullptr, nullptr);
}

// Round 7
// 157.776 us; speedup vs baseline: 2.7478x; 1.0321x over previous
//
#include <hip/hip_runtime.h>

typedef __attribute__((ext_vector_type(8))) short bf16x8;
typedef __attribute__((ext_vector_type(4))) float f32x4;
typedef __attribute__((ext_vector_type(16))) float f32x16;
typedef __attribute__((ext_vector_type(4))) int i32x4;
using u16 = unsigned short;

constexpr int Bsz = 4, T = 2048, C = 1024, H = 16, Dh = 64;
constexpr int Mrows = Bsz * T;   // 8192
constexpr int K_DIM = 1024;
// scores = (q.k)/sqrt(64); softmax in exp2 domain -> fold (1/8)*log2(e) into Q
constexpr float QSCALE = 0.18033688011112042f;

__device__ inline u16 f2bf(float f) {
    unsigned u = __builtin_bit_cast(unsigned, f);
    u += 0x7FFFu + ((u >> 16) & 1u);
    return (u16)(u >> 16);
}

__device__ inline void g2l16(const void* g, void* l) {
    __builtin_amdgcn_global_load_lds((const __attribute__((address_space(1))) void*)g,
                                     (__attribute__((address_space(3))) void*)l, 16, 0, 0);
}

// pack 2 f32 -> 2 bf16 in one u32 (lo -> low half)
__device__ inline unsigned pk2(float lo, float hi) {
    unsigned d;
    asm("v_cvt_pk_bf16_f32 %0, %1, %2" : "=v"(d) : "v"(lo), "v"(hi));
    return d;
}
// a' = (a.lo32lanes, b.lo32lanes); b' = (a.hi32lanes, b.hi32lanes)
__device__ inline void swap32(unsigned& a, unsigned& b) {
    asm("v_permlane32_swap_b32 %0, %1" : "+v"(a), "+v"(b));
}

// ---------------------------------------------------------------------------
// One-shot f32 -> bf16 conversion of x, w_qkv, w_out (memory-bound, ~14us).
// ---------------------------------------------------------------------------
__global__ __launch_bounds__(256)
void cvt_k(const float* __restrict__ x, const float* __restrict__ wq,
           const float* __restrict__ wo, u16* __restrict__ xb,
           u16* __restrict__ wqb, u16* __restrict__ wob)
{
    int idx = blockIdx.x * 256 + threadIdx.x;
    const float* src; u16* dst; int rel;
    if (idx < 1048576)      { src = x;  dst = xb;  rel = idx; }
    else if (idx < 1441792) { src = wq; dst = wqb; rel = idx - 1048576; }
    else                    { src = wo; dst = wob; rel = idx - 1441792; }
    size_t off = (size_t)rel * 8;
    float4 a = *(const float4*)(src + off);
    float4 b = *(const float4*)(src + off + 4);
    unsigned r0 = (unsigned)f2bf(a.x) | ((unsigned)f2bf(a.y) << 16);
    unsigned r1 = (unsigned)f2bf(a.z) | ((unsigned)f2bf(a.w) << 16);
    unsigned r2 = (unsigned)f2bf(b.x) | ((unsigned)f2bf(b.y) << 16);
    unsigned r3 = (unsigned)f2bf(b.z) | ((unsigned)f2bf(b.w) << 16);
    *(uint4*)(dst + off) = make_uint4(r0, r1, r2, r3);
}

// ---------------------------------------------------------------------------
// m97-structure GEMM body: C[M,N] = A[M,K] * B[N,K]^T, all-bf16 inputs.
// 128x128 tile, BK=64, 4 waves (2x2), global_load_lds dwordx4 staging with
// pre-swizzled global source (T2 both-sides), 2-barrier K-loop.
// MODE 0: -> Q,K bf16 (B,H,T,Dh), Q pre-scaled.   MODE 2: swapped mfma
// operands -> V^T (B,H,Dh,T).   MODE 1: bf16 attn-out -> f32 d_out.
// QK and V panels are merged into ONE kernel via a BLOCK-LEVEL branch (two
// complete loop bodies — NOT round-2's in-loop branch) for tail overlap.
// ---------------------------------------------------------------------------
__device__ inline void stage_g(u16* lds, const u16* gb, int ldg, int tid) {
    #pragma unroll
    for (int i = 0; i < 4; ++i) {
        int ch = i * 256 + tid;
        int r = ch >> 3, c8 = ch & 7;
        int sc = c8 ^ (r & 7);   // inverse-swizzled source, linear LDS dest
        g2l16(gb + (size_t)r * ldg + sc * 8, lds + (i * 256 + (tid & 192)) * 8);
    }
}

template<int MODE>
__device__ __forceinline__
void gemm_body(const u16* __restrict__ Ab, const u16* __restrict__ Bb,
               float* __restrict__ Op, u16* __restrict__ qws,
               u16* __restrict__ kws, u16* __restrict__ vtws,
               u16* As, u16* Bs, int m0, int n0)
{
    const int tid = threadIdx.x;
    const int l = tid & 63, wid = tid >> 6;
    const int wm = wid >> 1, wn = wid & 1;
    const int lane16 = l & 15, lhi = l >> 4;

    const u16* Abase = Ab + (size_t)m0 * K_DIM;
    const u16* Bbase = Bb + (size_t)n0 * K_DIM;

    f32x4 acc[4][4] = {};

    for (int ks = 0; ks < K_DIM / 64; ++ks) {
        __syncthreads();                       // previous compute done, LDS free
        stage_g(As, Abase + ks * 64, K_DIM, tid);
        stage_g(Bs, Bbase + ks * 64, K_DIM, tid);
        __syncthreads();                       // drains vmcnt(0): tiles visible
        #pragma unroll
        for (int kc = 0; kc < 2; kc++) {
            bf16x8 af[4], bfr[4];
            #pragma unroll
            for (int mi = 0; mi < 4; mi++) {
                int row = wm * 64 + mi * 16 + lane16;
                int byte = row * 128 + kc * 64 + lhi * 16; byte ^= (row & 7) << 4;
                af[mi] = *(const bf16x8*)((const char*)As + byte);
            }
            #pragma unroll
            for (int ni = 0; ni < 4; ni++) {
                int row = wn * 64 + ni * 16 + lane16;
                int byte = row * 128 + kc * 64 + lhi * 16; byte ^= (row & 7) << 4;
                bfr[ni] = *(const bf16x8*)((const char*)Bs + byte);
            }
            #pragma unroll
            for (int mi = 0; mi < 4; mi++)
                #pragma unroll
                for (int ni = 0; ni < 4; ni++) {
                    if constexpr (MODE == 2)
                        acc[mi][ni] = __builtin_amdgcn_mfma_f32_16x16x32_bf16(
                            bfr[ni], af[mi], acc[mi][ni], 0, 0, 0);
                    else
                        acc[mi][ni] = __builtin_amdgcn_mfma_f32_16x16x32_bf16(
                            af[mi], bfr[ni], acc[mi][ni], 0, 0, 0);
                }
        }
    }

    if constexpr (MODE == 2) {
        // D layout: regs = W rows (out-features), lanes = x rows (t)
        #pragma unroll
        for (int mi = 0; mi < 4; mi++)
            #pragma unroll
            for (int ni = 0; ni < 4; ni++)
                #pragma unroll
                for (int r = 0; r < 4; r++) {
                    int wr = n0 + wn * 64 + ni * 16 + lhi * 4 + r;  // 2048..3071
                    int tg = m0 + wm * 64 + mi * 16 + lane16;       // 0..8191
                    int hh = (wr >> 6) & 15, d = wr & 63;
                    int bb = tg >> 11, tt = tg & 2047;
                    size_t off = (((size_t)bb * H + hh) * Dh + d) * T + tt;
                    vtws[off] = f2bf(acc[mi][ni][r]);
                }
    } else {
        #pragma unroll
        for (int mi = 0; mi < 4; mi++)
            #pragma unroll
            for (int ni = 0; ni < 4; ni++)
                #pragma unroll
                for (int r = 0; r < 4; r++) {
                    int gm = m0 + wm * 64 + mi * 16 + lhi * 4 + r;
                    int gn = n0 + wn * 64 + ni * 16 + lane16;
                    float val = acc[mi][ni][r];
                    if constexpr (MODE == 0) {
                        int hh = (gn >> 6) & 15, d = gn & 63;
                        int bb = gm >> 11, t = gm & 2047;
                        size_t off = (((size_t)bb * H + hh) * T + t) * Dh + d;
                        if (gn < C) qws[off] = f2bf(val * QSCALE);
                        else        kws[off] = f2bf(val);
                    } else {
                        Op[(size_t)gm * C + gn] = val;
                    }
                }
    }
}

__global__ __launch_bounds__(256)
void gemm_qkv(const u16* __restrict__ xb, const u16* __restrict__ wqkvb,
              u16* __restrict__ qws, u16* __restrict__ kws, u16* __restrict__ vtws)
{
    __shared__ alignas(16) u16 As[128 * 64];
    __shared__ alignas(16) u16 Bs[128 * 64];
    const int m0 = blockIdx.x * 128;
    if (blockIdx.y < 16)
        gemm_body<0>(xb, wqkvb, nullptr, qws, kws, vtws, As, Bs, m0, blockIdx.y * 128);
    else
        gemm_body<2>(xb, wqkvb, nullptr, qws, kws, vtws, As, Bs, m0,
                     2 * C + (blockIdx.y - 16) * 128);
}

__global__ __launch_bounds__(256)
void gemm_out(const u16* __restrict__ ob, const u16* __restrict__ woutb,
              float* __restrict__ Op)
{
    __shared__ alignas(16) u16 As[128 * 64];
    __shared__ alignas(16) u16 Bs[128 * 64];
    gemm_body<1>(ob, woutb, Op, nullptr, nullptr, nullptr, As, Bs,
                 blockIdx.x * 128, blockIdx.y * 128);
}

// ---------------------------------------------------------------------------
// Flash attention, causal — swapped-QK 32x32, counted-vmcnt pipeline (T3/T4).
// One 128-row q-tile per block, grid 1024, longest-first, head = bid&63 so
// each head's 16 tiles share one XCD L2 (round-6 win: FETCH 147->26 MB).
// Round-7: replace per-step __syncthreads (vmcnt(0) drain = next tile's
// fetch latency inside EVERY step) with 3-buffer KV rotation + raw s_barrier
// + s_waitcnt vmcnt(4): tile t+1's 4 loads/wave stay in flight across the
// barrier; stage tile t+2 right after the barrier. Epilogue drains 4 -> 0.
// ---------------------------------------------------------------------------
__device__ inline bf16x8 ldsfrag(const u16* base, int row, int cc) {
    int byte = (row << 7) + (cc << 4); byte ^= (row & 7) << 4;
    return *(const bf16x8*)((const char*)base + byte);
}

// stage 64 rows x 128B (2 g2l16/thread), source chunk-swizzled so swizzled
// reads see row-major
__device__ inline void stage_t(u16* lds, const u16* gb, int rstride, int tid) {
    #pragma unroll
    for (int it = 0; it < 2; ++it) {
        int chunk = it * 256 + tid;
        int r = chunk >> 3, cc = chunk & 7;
        int sc = cc ^ (r & 7);
        g2l16(gb + (size_t)r * rstride + sc * 8, lds + (it * 256 + (tid & 192)) * 8);
    }
}

__global__ __launch_bounds__(256, 3)
void attn_k(const u16* __restrict__ qws, const u16* __restrict__ kws,
            const u16* __restrict__ vtws, u16* __restrict__ ows)
{
    __shared__ alignas(16) u16 KL[3][64 * 64];
    __shared__ alignas(16) u16 VL[3][64 * 64];

    const int bid = blockIdx.x;
    const int head = bid & 63;            // XCD = bid%8 = head%8 (L2 locality)
    const int qt = 15 - (bid >> 6);       // longest q-tiles dispatched first
    const int b = head >> 4, h = head & 15;
    const int tid = threadIdx.x, w = tid >> 6, l = tid & 63;
    const int l31 = l & 31, hi = l >> 5;

    const size_t hoff = (size_t)head * (T * Dh);
    const u16* Qg  = qws + hoff;
    const u16* Kg  = kws + hoff;
    const u16* Vtg = vtws + hoff;   // [Dh][T] per head

    const int qb = qt * 128;
    const int nt = 2 * qt + 2;
    const int qbw = qb + w * 32;          // this wave's 32 q rows

    // Q fragments (B-operand: row q = l&31, k = hi*8+j) — issued BEFORE the
    // staged prologue so vmcnt FIFO retires them first.
    bf16x8 qf[4];
    #pragma unroll
    for (int c = 0; c < 4; ++c)
        qf[c] = *(const bf16x8*)(Qg + (size_t)(qbw + l31) * Dh + c * 16 + hi * 8);

    f32x16 o0{}, o1{};                    // d 0..31 / 32..63
    float mrun = -__builtin_inff(), lrun = 0.f;

    // prologue: stage tiles 0 and 1 (nt >= 2 always) -> 8 loads/wave in flight
    stage_t(KL[0], Kg, Dh, tid);
    stage_t(VL[0], Vtg, T, tid);
    stage_t(KL[1], Kg + (size_t)64 * Dh, Dh, tid);
    stage_t(VL[1], Vtg + 64, T, tid);

    int cur = 0;
    for (int t = 0; t < nt; ++t) {
        // tile t ready when <=4 outstanding (t+1's stay in flight); drain at end
        if (t + 1 < nt) asm volatile("s_waitcnt vmcnt(4)" ::: "memory");
        else            asm volatile("s_waitcnt vmcnt(0)" ::: "memory");
        __builtin_amdgcn_s_barrier();
        __builtin_amdgcn_sched_barrier(0);

        int nx = cur + 2; if (nx >= 3) nx -= 3;
        if (t + 2 < nt) {                 // stage tile t+2 (buffer read at t-1)
            stage_t(KL[nx], Kg + (size_t)(t + 2) * 64 * Dh, Dh, tid);
            stage_t(VL[nx], Vtg + (t + 2) * 64, T, tid);
        }

        const int kv0 = t * 64;
        if (kv0 <= qbw + 31) {            // wave has unmasked work
            const u16* Kb = KL[cur];
            const u16* Vb = VL[cur];

            bf16x8 kf0[4], kf1[4];        // A-operand: kv rows 0..31 / 32..63
            #pragma unroll
            for (int c = 0; c < 4; ++c) {
                kf0[c] = ldsfrag(Kb, l31, c * 2 + hi);
                kf1[c] = ldsfrag(Kb, 32 + l31, c * 2 + hi);
            }

            f32x16 s0{}, s1{};
            #pragma unroll
            for (int c = 0; c < 4; ++c) {
                s0 = __builtin_amdgcn_mfma_f32_32x32x16_bf16(kf0[c], qf[c], s0, 0, 0, 0);
                s1 = __builtin_amdgcn_mfma_f32_32x32x16_bf16(kf1[c], qf[c], s1, 0, 0, 0);
            }

            if (kv0 + 63 > qbw) {         // diagonal: causal mask
                int qg = qbw + l31;
                #pragma unroll
                for (int r = 0; r < 16; ++r) {
                    int kvg = kv0 + (r & 3) + 8 * (r >> 2) + 4 * hi;
                    if (kvg > qg)      s0[r] = -__builtin_inff();
                    if (kvg + 32 > qg) s1[r] = -__builtin_inff();
                }
            }

            // ---- in-register online softmax (row q = l&31; pair l^32) ----
            float m16[16];
            #pragma unroll
            for (int r = 0; r < 16; ++r) m16[r] = fmaxf(s0[r], s1[r]);
            #pragma unroll
            for (int d = 8; d; d >>= 1)
                #pragma unroll
                for (int r = 0; r < d; ++r) m16[r] = fmaxf(m16[r], m16[r + d]);
            float pmax = fmaxf(m16[0], __shfl_xor(m16[0], 32));

            if (!__all(pmax - mrun <= 8.0f)) {   // T13 defer-max
                float mn = fmaxf(mrun, pmax);
                float corr = __builtin_amdgcn_exp2f(mrun - mn);
                mrun = mn;
                lrun *= corr;
                #pragma unroll
                for (int r = 0; r < 16; ++r) {
                    float cr = __shfl(corr, (r & 3) + 8 * (r >> 2) + 4 * hi);
                    o0[r] *= cr;
                    o1[r] *= cr;
                }
            }
            float p0[16], p1[16];
            float t0 = 0.f, t1 = 0.f, t2 = 0.f, t3 = 0.f;
            #pragma unroll
            for (int r = 0; r < 16; ++r) {
                p0[r] = __builtin_amdgcn_exp2f(s0[r] - mrun);
                p1[r] = __builtin_amdgcn_exp2f(s1[r] - mrun);
                float s = p0[r] + p1[r];
                if ((r & 3) == 0) t0 += s; else if ((r & 3) == 1) t1 += s;
                else if ((r & 3) == 2) t2 += s; else t3 += s;
            }
            lrun += (t0 + t1) + (t2 + t3);

            // ---- P -> bf16 A-frags (T12: cvt_pk + permlane32_swap) ----
            unsigned paf[4][4];
            unsigned cc[8];
            #pragma unroll
            for (int i = 0; i < 4; ++i) cc[i]     = pk2(p0[2 * i], p0[2 * i + 1]);
            #pragma unroll
            for (int i = 0; i < 4; ++i) cc[4 + i] = pk2(p0[8 + 2 * i], p0[9 + 2 * i]);
            swap32(cc[0], cc[2]); swap32(cc[1], cc[3]);
            swap32(cc[4], cc[6]); swap32(cc[5], cc[7]);
            #pragma unroll
            for (int i = 0; i < 4; ++i) { paf[0][i] = cc[i]; paf[1][i] = cc[4 + i]; }
            #pragma unroll
            for (int i = 0; i < 4; ++i) cc[i]     = pk2(p1[2 * i], p1[2 * i + 1]);
            #pragma unroll
            for (int i = 0; i < 4; ++i) cc[4 + i] = pk2(p1[8 + 2 * i], p1[9 + 2 * i]);
            swap32(cc[0], cc[2]); swap32(cc[1], cc[3]);
            swap32(cc[4], cc[6]); swap32(cc[5], cc[7]);
            #pragma unroll
            for (int i = 0; i < 4; ++i) { paf[2][i] = cc[i]; paf[3][i] = cc[4 + i]; }

            // ---- O += P V ----
            #pragma unroll
            for (int kb = 0; kb < 4; ++kb) {
                i32x4 wv = {(int)paf[kb][0], (int)paf[kb][1],
                            (int)paf[kb][2], (int)paf[kb][3]};
                bf16x8 pa = __builtin_bit_cast(bf16x8, wv);
                bf16x8 v0 = ldsfrag(Vb, l31,      kb * 2 + hi);
                bf16x8 v1 = ldsfrag(Vb, 32 + l31, kb * 2 + hi);
                o0 = __builtin_amdgcn_mfma_f32_32x32x16_bf16(pa, v0, o0, 0, 0, 0);
                o1 = __builtin_amdgcn_mfma_f32_32x32x16_bf16(pa, v1, o1, 0, 0, 0);
            }
        }
        cur = (cur == 2) ? 0 : cur + 1;
    }

    // ---- finalize ----
    float lt = lrun + __shfl_xor(lrun, 32);
    float inv = 1.0f / lt;
    #pragma unroll
    for (int r = 0; r < 16; ++r) {
        int cr = (r & 3) + 8 * (r >> 2) + 4 * hi;
        float il = __shfl(inv, cr);
        size_t rowoff = ((size_t)b * T + qb + w * 32 + cr) * C + h * Dh + l31;
        ows[rowoff]      = f2bf(o0[r] * il);
        ows[rowoff + 32] = f2bf(o1[r] * il);
    }
}

// ---------------------------------------------------------------------------
extern "C" void kernel_launch(void* const* d_in, const int* in_sizes, int n_in,
                              void* d_out, int out_size, void* d_ws, size_t ws_size,
                              hipStream_t stream)
{
    const float* x     = (const float*)d_in[0];
    const float* w_qkv = (const float*)d_in[1];
    const float* w_out = (const float*)d_in[2];
    float* out = (float*)d_out;

    const size_t SZ = (size_t)Bsz * H * T * Dh;  // 8388608 elems per tensor
    u16* qws   = (u16*)d_ws;
    u16* kws   = qws + SZ;
    u16* vtws  = kws + SZ;        // V transposed: [B][H][Dh][T]
    u16* xb    = vtws + SZ;       // x as bf16; ALIASED with ows (x consumed
    u16* ows   = xb;              //   by gemm_qkv before attn writes ows)
    u16* wqkvb = xb + SZ;         // w_qkv bf16 (3072x1024)
    u16* woutb = wqkvb + (size_t)3 * C * C;  // w_out bf16 (1024x1024)

    cvt_k<<<dim3(6144), 256, 0, stream>>>(x, w_qkv, w_out, xb, wqkvb, woutb);

    gemm_qkv<<<dim3(Mrows / 128, 24), 256, 0, stream>>>(xb, wqkvb, qws, kws, vtws);

    attn_k<<<dim3(1024), 256, 0, stream>>>(qws, kws, vtws, ows);

    gemm_out<<<dim3(Mrows / 128, C / 128), 256, 0, stream>>>(ows, woutb, out);
}